// Round 1
// baseline (4271.593 us; speedup 1.0000x reference)
//
#include <hip/hip_runtime.h>
#include <hip/hip_bf16.h>
#include <math.h>

#define HW 4096
#define WD 64
#define HD 64
#define CDIM 256
#define BATCH 8

enum { EPI_NONE = 0, EPI_SIGMOID = 1, EPI_GELU = 2, EPI_RES = 3 };

// Generic pointwise-channel GEMM over pixels:
//   Out[b, m, n] = epi( sum_k A[m,k] * In[b, k, n] + bias[m] )  for n in [0,HW)
// A[m,k] accessed as A[m*a_sm + k*a_sk] (handles W and W^T layouts).
__global__ __launch_bounds__(256) void gemm_pw(
    const float* __restrict__ A, int a_sm, int a_sk,
    const float* __restrict__ bias,
    const float* __restrict__ In, int K,
    float* __restrict__ Out, int M,
    const float* __restrict__ Res, int epi)
{
    __shared__ float As[16][64];
    __shared__ float Bs[16][64];
    const int tid = threadIdx.x;
    const int tx = tid & 15;        // n-group
    const int ty = tid >> 4;        // m-group
    const int n0 = blockIdx.x * 64;
    const int m0 = blockIdx.y * 64;
    const int bb = blockIdx.z;
    const float* InB = In + (size_t)bb * K * HW;

    float acc[4][4];
#pragma unroll
    for (int i = 0; i < 4; ++i)
#pragma unroll
        for (int j = 0; j < 4; ++j) acc[i][j] = 0.f;

    for (int k0 = 0; k0 < K; k0 += 16) {
#pragma unroll
        for (int l = 0; l < 4; ++l) {
            int idx = l * 256 + tid;
            int kk = idx >> 6;
            int mm = idx & 63;
            As[kk][mm] = A[(size_t)(m0 + mm) * a_sm + (size_t)(k0 + kk) * a_sk];
            Bs[kk][mm] = InB[(size_t)(k0 + kk) * HW + n0 + mm];
        }
        __syncthreads();
#pragma unroll
        for (int kk = 0; kk < 16; ++kk) {
            float av[4], bv[4];
#pragma unroll
            for (int i = 0; i < 4; ++i) av[i] = As[kk][ty + 16 * i];
#pragma unroll
            for (int j = 0; j < 4; ++j) bv[j] = Bs[kk][tx + 16 * j];
#pragma unroll
            for (int i = 0; i < 4; ++i)
#pragma unroll
                for (int j = 0; j < 4; ++j) acc[i][j] += av[i] * bv[j];
        }
        __syncthreads();
    }

#pragma unroll
    for (int i = 0; i < 4; ++i) {
        int m = m0 + ty + 16 * i;
        float bs = bias ? bias[m] : 0.f;
#pragma unroll
        for (int j = 0; j < 4; ++j) {
            int n = n0 + tx + 16 * j;
            float v = acc[i][j] + bs;
            size_t o = ((size_t)bb * M + m) * HW + n;
            if (epi == EPI_SIGMOID)      v = 1.f / (1.f + expf(-v));
            else if (epi == EPI_GELU)    v = 0.5f * v * (1.f + erff(v * 0.70710678118654752f));
            else if (epi == EPI_RES)     v += Res[o];
            Out[o] = v;
        }
    }
}

// Directional tridiagonal gated scan. One 64-lane wave per (b,c) plane.
// w3:  [B, 3, C, H*W]  raw taps (normalized here: / (sum|taps| + 1e-6))
// lam: [B, C, H*W]     (already sigmoided)
// u:   [B, C, H*W]
// y:   [B, C, H*W]     overwrite (dir 0) or accumulate (dirs 1..3)
// dir 0: rows top->down (lane = w); dir 1: rows bottom->up (lane = w)
// dir 2: cols left->right (lane = h); dir 3: cols right->left (lane = h)
__global__ __launch_bounds__(256) void scan_dir(
    const float* __restrict__ w3,
    const float* __restrict__ lam,
    const float* __restrict__ u,
    float* __restrict__ y,
    int dir, int overwrite)
{
    const int wave = threadIdx.x >> 6;
    const int lane = threadIdx.x & 63;
    const int plane = blockIdx.x * 4 + wave;   // 0..2047
    const int b = plane >> 8;
    const int c = plane & 255;

    const size_t base_cu = ((size_t)b * CDIM + c) * HW;
    const size_t base_w  = ((size_t)b * 3 * CDIM + c) * HW;
    const size_t tapstr  = (size_t)CDIM * HW;

    float h = 0.f;
    for (int s = 0; s < 64; ++s) {
        const int p = (dir == 1 || dir == 3) ? (63 - s) : s;
        const size_t off = (dir < 2) ? ((size_t)p * WD + lane)
                                     : ((size_t)lane * WD + p);
        float w0 = w3[base_w + off];
        float w1 = w3[base_w + tapstr + off];
        float w2 = w3[base_w + 2 * tapstr + off];
        float dn = 1.0f / (fabsf(w0) + fabsf(w1) + fabsf(w2) + 1e-6f);
        float lm = lam[base_cu + off];
        float uu = u[base_cu + off];

        float hl = __shfl_up(h, 1);
        float hr = __shfl_down(h, 1);
        if (lane == 0)  hl = 0.f;
        if (lane == 63) hr = 0.f;

        h = (w0 * hl + w1 * h + w2 * hr) * dn + lm * uu;

        if (overwrite) y[base_cu + off] = h;
        else           y[base_cu + off] += h;
    }
}

extern "C" void kernel_launch(void* const* d_in, const int* in_sizes, int n_in,
                              void* d_out, int out_size, void* d_ws, size_t ws_size,
                              hipStream_t stream)
{
    const float* x  = (const float*)d_in[0];
    const float* Wu = (const float*)d_in[1];
    const float* bu = (const float*)d_in[2];
    const float* Ww = (const float*)d_in[3];
    const float* bw = (const float*)d_in[4];
    const float* Wl = (const float*)d_in[5];
    const float* bl = (const float*)d_in[6];
    const float* Wo = (const float*)d_in[7];
    const float* bo = (const float*)d_in[8];
    const float* W1 = (const float*)d_in[9];
    const float* b1 = (const float*)d_in[10];
    const float* W2 = (const float*)d_in[11];
    const float* b2 = (const float*)d_in[12];
    float* out = (float*)d_out;

    const size_t NPLANE = (size_t)BATCH * CDIM * HW;       // 8.39M floats
    float* ws   = (float*)d_ws;
    float* u_   = ws;
    float* w_i  = u_ + NPLANE;                             // [B,768,HW] per-direction raw taps
    float* lam_ = w_i + (size_t)BATCH * 768 * HW;
    float* y_   = lam_ + NPLANE;
    float* x2_  = y_ + NPLANE;
    float* h_   = w_i;                                     // reuse w_i+lam_ region for MLP hidden [B,1024,HW]

    dim3 blk(256);

    // u = Wu @ x + bu
    gemm_pw<<<dim3(64, 4, 8), blk, 0, stream>>>(Wu, 256, 1, bu, x, 256, u_, 256, nullptr, EPI_NONE);

    for (int dir = 0; dir < 4; ++dir) {
        // raw taps for this direction: rows [dir*768, dir*768+768) of Ww
        gemm_pw<<<dim3(64, 12, 8), blk, 0, stream>>>(
            Ww + (size_t)dir * 768 * 256, 256, 1, bw + dir * 768, x, 256, w_i, 768, nullptr, EPI_NONE);
        // lam for this direction: rows [dir*256, dir*256+256) of Wl, sigmoid epilogue
        gemm_pw<<<dim3(64, 4, 8), blk, 0, stream>>>(
            Wl + (size_t)dir * 256 * 256, 256, 1, bl + dir * 256, x, 256, lam_, 256, nullptr, EPI_SIGMOID);
        // scan this direction into y (dir 0 overwrites, others accumulate)
        scan_dir<<<dim3(512), blk, 0, stream>>>(w_i, lam_, u_, y_, dir, dir == 0 ? 1 : 0);
    }

    // x2 = x + Wo @ y + bo
    gemm_pw<<<dim3(64, 4, 8), blk, 0, stream>>>(Wo, 256, 1, bo, y_, 256, x2_, 256, x, EPI_RES);
    // h = gelu(x2 @ W1 + b1)   (A[m,k] = W1[k,m] -> a_sm=1, a_sk=1024)
    gemm_pw<<<dim3(64, 16, 8), blk, 0, stream>>>(W1, 1, 1024, b1, x2_, 256, h_, 1024, nullptr, EPI_GELU);
    // out = x2 + h @ W2 + b2   (A[m,k] = W2[k,m] -> a_sm=1, a_sk=256)
    gemm_pw<<<dim3(64, 4, 8), blk, 0, stream>>>(W2, 1, 256, b2, h_, 1024, out, 256, x2_, EPI_RES);
}

// Round 4
// 2353.457 us; speedup vs baseline: 1.8150x; 1.8150x over previous
//
#include <hip/hip_runtime.h>
#include <hip/hip_bf16.h>
#include <math.h>

#define HW 4096
#define WD 64
#define HD 64
#define CDIM 256
#define BATCH 8
#define CH 16

enum { EPI_NONE = 0, EPI_SIGMOID = 1, EPI_GELU = 2, EPI_RES = 3 };

// Generic pointwise-channel GEMM over pixels:
//   Out[b, m, n] = epi( sum_k A[m,k] * In[b, k, n] + bias[m] )  for n in [0,HW)
// A[m,k] accessed as A[m*a_sm + k*a_sk] (handles W and W^T layouts).
__global__ __launch_bounds__(256) void gemm_pw(
    const float* __restrict__ A, int a_sm, int a_sk,
    const float* __restrict__ bias,
    const float* __restrict__ In, int K,
    float* __restrict__ Out, int M,
    const float* __restrict__ Res, int epi)
{
    __shared__ float As[16][64];
    __shared__ float Bs[16][64];
    const int tid = threadIdx.x;
    const int tx = tid & 15;        // n-group
    const int ty = tid >> 4;        // m-group
    const int n0 = blockIdx.x * 64;
    const int m0 = blockIdx.y * 64;
    const int bb = blockIdx.z;
    const float* InB = In + (size_t)bb * K * HW;

    float acc[4][4];
#pragma unroll
    for (int i = 0; i < 4; ++i)
#pragma unroll
        for (int j = 0; j < 4; ++j) acc[i][j] = 0.f;

    for (int k0 = 0; k0 < K; k0 += 16) {
#pragma unroll
        for (int l = 0; l < 4; ++l) {
            int idx = l * 256 + tid;
            int kk = idx >> 6;
            int mm = idx & 63;
            As[kk][mm] = A[(size_t)(m0 + mm) * a_sm + (size_t)(k0 + kk) * a_sk];
            Bs[kk][mm] = InB[(size_t)(k0 + kk) * HW + n0 + mm];
        }
        __syncthreads();
#pragma unroll
        for (int kk = 0; kk < 16; ++kk) {
            float av[4], bv[4];
#pragma unroll
            for (int i = 0; i < 4; ++i) av[i] = As[kk][ty + 16 * i];
#pragma unroll
            for (int j = 0; j < 4; ++j) bv[j] = Bs[kk][tx + 16 * j];
#pragma unroll
            for (int i = 0; i < 4; ++i)
#pragma unroll
                for (int j = 0; j < 4; ++j) acc[i][j] += av[i] * bv[j];
        }
        __syncthreads();
    }

#pragma unroll
    for (int i = 0; i < 4; ++i) {
        int m = m0 + ty + 16 * i;
        float bs = bias ? bias[m] : 0.f;
#pragma unroll
        for (int j = 0; j < 4; ++j) {
            int n = n0 + tx + 16 * j;
            float v = acc[i][j] + bs;
            size_t o = ((size_t)bb * M + m) * HW + n;
            if (epi == EPI_SIGMOID)      v = 1.f / (1.f + expf(-v));
            else if (epi == EPI_GELU)    v = 0.5f * v * (1.f + erff(v * 0.70710678118654752f));
            else if (epi == EPI_RES)     v += Res[o];
            Out[o] = v;
        }
    }
}

// Row-direction scans (dirs 0/1): lane = w (contiguous), scan over h. Coalesced.
__global__ __launch_bounds__(256) void scan_dir(
    const float* __restrict__ w3,
    const float* __restrict__ lam,
    const float* __restrict__ u,
    float* __restrict__ y,
    int dir, int overwrite)
{
    const int wave = threadIdx.x >> 6;
    const int lane = threadIdx.x & 63;
    const int plane = blockIdx.x * 4 + wave;   // 0..2047
    const int b = plane >> 8;
    const int c = plane & 255;

    const size_t base_cu = ((size_t)b * CDIM + c) * HW;
    const size_t base_w  = ((size_t)b * 3 * CDIM + c) * HW;
    const size_t tapstr  = (size_t)CDIM * HW;

    float h = 0.f;
    for (int s = 0; s < 64; ++s) {
        const int p = (dir == 1) ? (63 - s) : s;
        const size_t off = (size_t)p * WD + lane;
        float w0 = w3[base_w + off];
        float w1 = w3[base_w + tapstr + off];
        float w2 = w3[base_w + 2 * tapstr + off];
        float dn = 1.0f / (fabsf(w0) + fabsf(w1) + fabsf(w2) + 1e-6f);
        float lm = lam[base_cu + off];
        float uu = u[base_cu + off];

        float hl = __shfl_up(h, 1);
        float hr = __shfl_down(h, 1);
        if (lane == 0)  hl = 0.f;
        if (lane == 63) hr = 0.f;

        h = (w0 * hl + w1 * h + w2 * hr) * dn + lm * uu;

        if (overwrite) y[base_cu + off] = h;
        else           y[base_cu + off] += h;
    }
}

// Column-direction scans (dirs 2/3): lane = h (stride-64 in memory), scan over w.
// LDS-tiled: per wave, stage [64 h][16 w] tiles of {w0,w1,w2,lam,u} with
// coalesced float4 loads, scan 16 steps out of LDS, overwrite the u tile with
// h, then coalesced float4 read-modify-write of y. Rows padded to 17 floats:
// column reads hit banks (17*lane)%32 -> exactly 2 lanes/bank = free.
__global__ __launch_bounds__(128) void scan_dir_t(
    const float* __restrict__ w3,
    const float* __restrict__ lam,
    const float* __restrict__ u,
    float* __restrict__ y,
    int dir)
{
    __shared__ float T[2][5][64][CH + 1];   // 43.5 KB
    const int wv = threadIdx.x >> 6;
    const int lane = threadIdx.x & 63;
    const int plane = blockIdx.x * 2 + wv;  // 0..2047
    const int b = plane >> 8;
    const int c = plane & 255;

    const size_t base_cu = ((size_t)b * CDIM + c) * HW;
    const size_t base_w  = ((size_t)b * 3 * CDIM + c) * HW;
    const size_t tapstr  = (size_t)CDIM * HW;
    const int rr = lane >> 2;   // 0..15 row sub-index
    const int q  = lane & 3;    // float4 slot within the 16-float row chunk

    const float* srcs[5];
    srcs[0] = w3 + base_w;
    srcs[1] = w3 + base_w + tapstr;
    srcs[2] = w3 + base_w + 2 * tapstr;
    srcs[3] = lam + base_cu;
    srcs[4] = u + base_cu;

    float h = 0.f;
    for (int ci = 0; ci < 4; ++ci) {
        const int p0 = (dir == 3) ? (48 - ci * 16) : (ci * 16);

        // Stage 5 tiles: element [r][cc] = src[r*64 + p0 + cc]
#pragma unroll
        for (int a = 0; a < 5; ++a) {
            const float* s = srcs[a];
#pragma unroll
            for (int i = 0; i < 4; ++i) {
                const int r = i * 16 + rr;
                const float4 v = *(const float4*)(s + (size_t)r * WD + p0 + q * 4);
                T[wv][a][r][q * 4 + 0] = v.x;
                T[wv][a][r][q * 4 + 1] = v.y;
                T[wv][a][r][q * 4 + 2] = v.z;
                T[wv][a][r][q * 4 + 3] = v.w;
            }
        }
        // same-wave LDS ops are processed in order; no cross-wave sharing.

        // Scan 16 steps (reversed within chunk for dir 3)
        for (int t = 0; t < CH; ++t) {
            const int pp = (dir == 3) ? (CH - 1 - t) : t;
            float w0 = T[wv][0][lane][pp];
            float w1 = T[wv][1][lane][pp];
            float w2 = T[wv][2][lane][pp];
            float dn = 1.0f / (fabsf(w0) + fabsf(w1) + fabsf(w2) + 1e-6f);
            float lm = T[wv][3][lane][pp];
            float uu = T[wv][4][lane][pp];

            float hl = __shfl_up(h, 1);
            float hr = __shfl_down(h, 1);
            if (lane == 0)  hl = 0.f;
            if (lane == 63) hr = 0.f;

            h = (w0 * hl + w1 * h + w2 * hr) * dn + lm * uu;
            T[wv][4][lane][pp] = h;     // overwrite consumed u slot with output
        }

        // Coalesced accumulate into y
#pragma unroll
        for (int i = 0; i < 4; ++i) {
            const int r = i * 16 + rr;
            const size_t g = base_cu + (size_t)r * WD + p0 + q * 4;
            float4 old = *(const float4*)(y + g);
            old.x += T[wv][4][r][q * 4 + 0];
            old.y += T[wv][4][r][q * 4 + 1];
            old.z += T[wv][4][r][q * 4 + 2];
            old.w += T[wv][4][r][q * 4 + 3];
            *(float4*)(y + g) = old;
        }
    }
}

extern "C" void kernel_launch(void* const* d_in, const int* in_sizes, int n_in,
                              void* d_out, int out_size, void* d_ws, size_t ws_size,
                              hipStream_t stream)
{
    const float* x  = (const float*)d_in[0];
    const float* Wu = (const float*)d_in[1];
    const float* bu = (const float*)d_in[2];
    const float* Ww = (const float*)d_in[3];
    const float* bw = (const float*)d_in[4];
    const float* Wl = (const float*)d_in[5];
    const float* bl = (const float*)d_in[6];
    const float* Wo = (const float*)d_in[7];
    const float* bo = (const float*)d_in[8];
    const float* W1 = (const float*)d_in[9];
    const float* b1 = (const float*)d_in[10];
    const float* W2 = (const float*)d_in[11];
    const float* b2 = (const float*)d_in[12];
    float* out = (float*)d_out;

    const size_t NPLANE = (size_t)BATCH * CDIM * HW;       // 8.39M floats
    float* ws   = (float*)d_ws;
    float* u_   = ws;
    float* w_i  = u_ + NPLANE;                             // [B,768,HW] per-direction raw taps
    float* lam_ = w_i + (size_t)BATCH * 768 * HW;
    float* y_   = lam_ + NPLANE;
    float* x2_  = y_ + NPLANE;
    float* h_   = w_i;                                     // reuse w_i+lam_ region for MLP hidden [B,1024,HW]

    dim3 blk(256);

    // u = Wu @ x + bu
    gemm_pw<<<dim3(64, 4, 8), blk, 0, stream>>>(Wu, 256, 1, bu, x, 256, u_, 256, nullptr, EPI_NONE);

    for (int dir = 0; dir < 4; ++dir) {
        // raw taps for this direction: rows [dir*768, dir*768+768) of Ww
        gemm_pw<<<dim3(64, 12, 8), blk, 0, stream>>>(
            Ww + (size_t)dir * 768 * 256, 256, 1, bw + dir * 768, x, 256, w_i, 768, nullptr, EPI_NONE);
        // lam for this direction: rows [dir*256, dir*256+256) of Wl, sigmoid epilogue
        gemm_pw<<<dim3(64, 4, 8), blk, 0, stream>>>(
            Wl + (size_t)dir * 256 * 256, 256, 1, bl + dir * 256, x, 256, lam_, 256, nullptr, EPI_SIGMOID);
        // scan this direction into y (dir 0 overwrites, others accumulate)
        if (dir < 2)
            scan_dir<<<dim3(512), blk, 0, stream>>>(w_i, lam_, u_, y_, dir, dir == 0 ? 1 : 0);
        else
            scan_dir_t<<<dim3(1024), dim3(128), 0, stream>>>(w_i, lam_, u_, y_, dir);
    }

    // x2 = x + Wo @ y + bo
    gemm_pw<<<dim3(64, 4, 8), blk, 0, stream>>>(Wo, 256, 1, bo, y_, 256, x2_, 256, x, EPI_RES);
    // h = gelu(x2 @ W1 + b1)   (A[m,k] = W1[k,m] -> a_sm=1, a_sk=1024)
    gemm_pw<<<dim3(64, 16, 8), blk, 0, stream>>>(W1, 1, 1024, b1, x2_, 256, h_, 1024, nullptr, EPI_GELU);
    // out = x2 + h @ W2 + b2   (A[m,k] = W2[k,m] -> a_sm=1, a_sk=256)
    gemm_pw<<<dim3(64, 4, 8), blk, 0, stream>>>(W2, 1, 256, b2, h_, 1024, out, 256, x2_, EPI_RES);
}

// Round 5
// 812.784 us; speedup vs baseline: 5.2555x; 2.8956x over previous
//
#include <hip/hip_runtime.h>
#include <hip/hip_bf16.h>
#include <math.h>

#define HW 4096
#define WD 64
#define CDIM 256
#define BATCH 8
#define CH 16

typedef __attribute__((ext_vector_type(8))) short s16x8;
typedef __attribute__((ext_vector_type(8))) __bf16 b16x8;
typedef __attribute__((ext_vector_type(4))) float f32x4;

enum { E_NONE = 0, E_SIG768 = 1, E_GELU = 2, E_RES = 3 };

__device__ __forceinline__ unsigned short f2bf(float f) {
    union { float f; unsigned u; } v; v.f = f;
    unsigned r = (v.u + 0x7fffu + ((v.u >> 16) & 1u)) >> 16;
    return (unsigned short)r;
}

__device__ __forceinline__ void gload16(const void* g, void* l) {
    __builtin_amdgcn_global_load_lds(
        (const __attribute__((address_space(1))) void*)g,
        (__attribute__((address_space(3))) void*)l, 16, 0, 0);
}

__device__ __forceinline__ f32x4 mfma_bf16(s16x8 a, s16x8 b, f32x4 c) {
    return __builtin_amdgcn_mfma_f32_16x16x32_bf16(
        __builtin_bit_cast(b16x8, a), __builtin_bit_cast(b16x8, b), c, 0, 0, 0);
}

// Pack all weights to bf16 [M][K] row-major blocks + packed bias vector.
// Wt layout (bf16 elems): u@0(64K), dir d@65536+d*262144(4x256K), o@1114112,
// W1t@1179648 (A[m][k]=W1[k][m]), W2t@1441792 (A[m][k]=W2[k][m]).
__global__ __launch_bounds__(256) void pack_weights(
    const float* __restrict__ Wu, const float* __restrict__ Ww,
    const float* __restrict__ Wl, const float* __restrict__ Wo,
    const float* __restrict__ W1, const float* __restrict__ W2,
    const float* __restrict__ bu, const float* __restrict__ bw,
    const float* __restrict__ bl, const float* __restrict__ bo,
    const float* __restrict__ b1, const float* __restrict__ b2,
    unsigned short* __restrict__ Wt, float* __restrict__ biasP)
{
    const int gid = blockIdx.x * 256 + threadIdx.x;
    if (gid < 1703936) {
        float v;
        if (gid < 65536) { v = Wu[gid]; }
        else if (gid < 1114112) {
            int t = gid - 65536; int d = t >> 18; int r = t & 262143;
            int m = r >> 8; int k = r & 255;
            v = (m < 768) ? Ww[(size_t)(d * 768 + m) * 256 + k]
                          : Wl[(size_t)(d * 256 + (m - 768)) * 256 + k];
        }
        else if (gid < 1179648) { v = Wo[gid - 1114112]; }
        else if (gid < 1441792) {
            int t = gid - 1179648; int m = t >> 8; int k = t & 255;
            v = W1[(size_t)k * 1024 + m];
        }
        else {
            int t = gid - 1441792; int m = t >> 10; int k = t & 1023;
            v = W2[(size_t)k * 256 + m];
        }
        Wt[gid] = f2bf(v);
    }
    if (gid < 5888) {
        float v;
        if (gid < 256) v = bu[gid];
        else if (gid < 4352) {
            int t = gid - 256; int d = t >> 10; int r = t & 1023;
            v = (r < 768) ? bw[d * 768 + r] : bl[d * 256 + (r - 768)];
        }
        else if (gid < 4608) v = bo[gid - 4352];
        else if (gid < 5632) v = b1[gid - 4608];
        else v = b2[gid - 5632];
        biasP[gid] = v;
    }
}

// fp32 channel-major [B][256][4096] -> bf16 pixel-major [B][4096][256]
__global__ __launch_bounds__(256) void transpose_to_bf(
    const float* __restrict__ src, unsigned short* __restrict__ dst)
{
    __shared__ float T[64][65];
    const int t = threadIdx.x;
    const int n0 = blockIdx.x * 64, c0 = blockIdx.y * 64, b = blockIdx.z;
    const int nl = t & 63, cg = t >> 6;
#pragma unroll
    for (int i = 0; i < 16; ++i) {
        int cl = cg + i * 4;
        T[cl][nl] = src[((size_t)b * 256 + c0 + cl) * HW + n0 + nl];
    }
    __syncthreads();
#pragma unroll
    for (int i = 0; i < 16; ++i) {
        int nl2 = cg + i * 4;
        dst[((size_t)b * HW + n0 + nl2) * 256 + c0 + (t & 63)] = f2bf(T[t & 63][nl2]);
    }
}

// MFMA GEMM: for each batch b, pixel n, channel m:
//   acc = sum_k Abf[b][n][k] * Wbf[m][k]   (bf16 in, fp32 accum)
//   v = epi(acc + bias[m] [+ resCM])  -> outCM [B][M][4096] f32 and/or
//                                        outPM [B][4096][M] bf16
// 128(pixels) x 128(channels) tile, 4 waves 2x2, 16x16x32 MFMA, BK=32.
__global__ __launch_bounds__(256) void gemm_mfma(
    const unsigned short* __restrict__ Abf,
    const unsigned short* __restrict__ Wbf,
    const float* __restrict__ bias,
    int K, int M,
    float* __restrict__ outCM,
    unsigned short* __restrict__ outPM,
    const float* __restrict__ resCM,
    int epi)
{
    __shared__ __align__(16) short At[128 * 32];   // 8 KB, rows = pixels, 32 k
    __shared__ __align__(16) short Bt[128 * 32];   // 8 KB, rows = channels
    const int tid = threadIdx.x;
    const int w = tid >> 6, l = tid & 63;
    const int n0 = blockIdx.x * 128;
    const int m0 = blockIdx.y * 128;
    const int bz = blockIdx.z;
    const int wpi = w >> 1, wcj = w & 1;          // wave 2x2 position
    const int lr = l & 15, lg = l >> 4;           // frag row/col, k-group

    const unsigned short* Ab = Abf + (size_t)bz * HW * K;

    f32x4 acc[4][4];
#pragma unroll
    for (int i = 0; i < 4; ++i)
#pragma unroll
        for (int j = 0; j < 4; ++j) acc[i][j] = (f32x4)0.f;

    const int sko = (l & 3) * 8;                  // lane k-offset (elems)
    for (int k0 = 0; k0 < K; k0 += 32) {
#pragma unroll
        for (int cc = 0; cc < 2; ++cc) {
            const int c = w * 2 + cc;             // chunk 0..7, wave-uniform
            const int row = c * 16 + (l >> 2);    // per-lane global row
            gload16(Ab  + (size_t)(n0 + row) * K + k0 + sko, (char*)At + c * 1024);
            gload16(Wbf + (size_t)(m0 + row) * K + k0 + sko, (char*)Bt + c * 1024);
        }
        __syncthreads();                          // drains vmcnt -> LDS ready
        s16x8 av[4], bv[4];
#pragma unroll
        for (int f = 0; f < 4; ++f) {
            av[f] = *(const s16x8*)&At[(wpi * 64 + f * 16 + lr) * 32 + lg * 8];
            bv[f] = *(const s16x8*)&Bt[(wcj * 64 + f * 16 + lr) * 32 + lg * 8];
        }
#pragma unroll
        for (int fi = 0; fi < 4; ++fi)
#pragma unroll
            for (int fj = 0; fj < 4; ++fj)
                acc[fi][fj] = mfma_bf16(av[fi], bv[fj], acc[fi][fj]);
        __syncthreads();                          // protect LDS reuse
    }

#pragma unroll
    for (int fi = 0; fi < 4; ++fi) {
#pragma unroll
        for (int fj = 0; fj < 4; ++fj) {
            const int m = m0 + wcj * 64 + fj * 16 + lr;
            const float bs = bias[m];
#pragma unroll
            for (int r = 0; r < 4; ++r) {
                const int n = n0 + wpi * 64 + fi * 16 + lg * 4 + r;
                float v = acc[fi][fj][r] + bs;
                if (epi == E_SIG768)      { if (m >= 768) v = 1.f / (1.f + expf(-v)); }
                else if (epi == E_GELU)   v = 0.5f * v * (1.f + erff(v * 0.70710678118654752f));
                else if (epi == E_RES)    v += resCM[((size_t)bz * M + m) * HW + n];
                if (outCM) outCM[((size_t)bz * M + m) * HW + n] = v;
                if (outPM) outPM[((size_t)bz * HW + n) * M + m] = f2bf(v);
            }
        }
    }
}

// Row-direction scans (dirs 0/1). w3/lam live in wl_ ([B][1024][HW] f32):
// per-batch stride 1024*HW for w3/lam, 256*HW for u/y. lam ptr pre-offset.
__global__ __launch_bounds__(256) void scan_dir(
    const float* __restrict__ w3,
    const float* __restrict__ lam,
    const float* __restrict__ u,
    float* __restrict__ y,
    int dir, int overwrite)
{
    const int wave = threadIdx.x >> 6;
    const int lane = threadIdx.x & 63;
    const int plane = blockIdx.x * 4 + wave;
    const int b = plane >> 8;
    const int c = plane & 255;

    const size_t base_w = (size_t)b * (1024 * HW) + (size_t)c * HW;
    const size_t base_u = ((size_t)b * CDIM + c) * HW;
    const size_t tapstr = (size_t)CDIM * HW;

    float h = 0.f;
    for (int s = 0; s < 64; ++s) {
        const int p = (dir == 1) ? (63 - s) : s;
        const size_t off = (size_t)p * WD + lane;
        float w0 = w3[base_w + off];
        float w1 = w3[base_w + tapstr + off];
        float w2 = w3[base_w + 2 * tapstr + off];
        float dn = 1.0f / (fabsf(w0) + fabsf(w1) + fabsf(w2) + 1e-6f);
        float lm = lam[base_w + off];
        float uu = u[base_u + off];

        float hl = __shfl_up(h, 1);
        float hr = __shfl_down(h, 1);
        if (lane == 0)  hl = 0.f;
        if (lane == 63) hr = 0.f;

        h = (w0 * hl + w1 * h + w2 * hr) * dn + lm * uu;

        if (overwrite) y[base_u + off] = h;
        else           y[base_u + off] += h;
    }
}

// Column-direction scans (dirs 2/3), LDS-tiled (validated round 1/4).
__global__ __launch_bounds__(128) void scan_dir_t(
    const float* __restrict__ w3,
    const float* __restrict__ lam,
    const float* __restrict__ u,
    float* __restrict__ y,
    int dir)
{
    __shared__ float T[2][5][64][CH + 1];
    const int wv = threadIdx.x >> 6;
    const int lane = threadIdx.x & 63;
    const int plane = blockIdx.x * 2 + wv;
    const int b = plane >> 8;
    const int c = plane & 255;

    const size_t base_w = (size_t)b * (1024 * HW) + (size_t)c * HW;
    const size_t base_u = ((size_t)b * CDIM + c) * HW;
    const size_t tapstr = (size_t)CDIM * HW;
    const int rr = lane >> 2;
    const int q  = lane & 3;

    const float* srcs[5];
    srcs[0] = w3 + base_w;
    srcs[1] = w3 + base_w + tapstr;
    srcs[2] = w3 + base_w + 2 * tapstr;
    srcs[3] = lam + base_w;
    srcs[4] = u + base_u;

    float h = 0.f;
    for (int ci = 0; ci < 4; ++ci) {
        const int p0 = (dir == 3) ? (48 - ci * 16) : (ci * 16);
#pragma unroll
        for (int a = 0; a < 5; ++a) {
            const float* s = srcs[a];
#pragma unroll
            for (int i = 0; i < 4; ++i) {
                const int r = i * 16 + rr;
                const float4 v = *(const float4*)(s + (size_t)r * WD + p0 + q * 4);
                T[wv][a][r][q * 4 + 0] = v.x;
                T[wv][a][r][q * 4 + 1] = v.y;
                T[wv][a][r][q * 4 + 2] = v.z;
                T[wv][a][r][q * 4 + 3] = v.w;
            }
        }
        for (int t = 0; t < CH; ++t) {
            const int pp = (dir == 3) ? (CH - 1 - t) : t;
            float w0 = T[wv][0][lane][pp];
            float w1 = T[wv][1][lane][pp];
            float w2 = T[wv][2][lane][pp];
            float dn = 1.0f / (fabsf(w0) + fabsf(w1) + fabsf(w2) + 1e-6f);
            float lm = T[wv][3][lane][pp];
            float uu = T[wv][4][lane][pp];

            float hl = __shfl_up(h, 1);
            float hr = __shfl_down(h, 1);
            if (lane == 0)  hl = 0.f;
            if (lane == 63) hr = 0.f;

            h = (w0 * hl + w1 * h + w2 * hr) * dn + lm * uu;
            T[wv][4][lane][pp] = h;
        }
#pragma unroll
        for (int i = 0; i < 4; ++i) {
            const int r = i * 16 + rr;
            const size_t g = base_u + (size_t)r * WD + p0 + q * 4;
            float4 old = *(const float4*)(y + g);
            old.x += T[wv][4][r][q * 4 + 0];
            old.y += T[wv][4][r][q * 4 + 1];
            old.z += T[wv][4][r][q * 4 + 2];
            old.w += T[wv][4][r][q * 4 + 3];
            *(float4*)(y + g) = old;
        }
    }
}

extern "C" void kernel_launch(void* const* d_in, const int* in_sizes, int n_in,
                              void* d_out, int out_size, void* d_ws, size_t ws_size,
                              hipStream_t stream)
{
    const float* x  = (const float*)d_in[0];
    const float* Wu = (const float*)d_in[1];
    const float* bu = (const float*)d_in[2];
    const float* Ww = (const float*)d_in[3];
    const float* bw = (const float*)d_in[4];
    const float* Wl = (const float*)d_in[5];
    const float* bl = (const float*)d_in[6];
    const float* Wo = (const float*)d_in[7];
    const float* bo = (const float*)d_in[8];
    const float* W1 = (const float*)d_in[9];
    const float* b1 = (const float*)d_in[10];
    const float* W2 = (const float*)d_in[11];
    const float* b2 = (const float*)d_in[12];
    float* out = (float*)d_out;

    // ws layout (255.1 MB total; 268 MB proven available in round 1):
    float* ws_f = (float*)d_ws;
    float* wl_  = ws_f;                                  // [8][1024][4096] f32 (taps+lam per dir)
    float* u_   = ws_f + 33554432;                       // [8][256][4096] f32; later x2c
    float* y_   = u_ + 8388608;                          // [8][256][4096] f32
    unsigned short* xT  = (unsigned short*)(y_ + 8388608);  // [8][4096][256] bf16
    unsigned short* yT  = xT + 8388608;
    unsigned short* x2T = yT + 8388608;
    unsigned short* Wt  = x2T + 8388608;                 // packed weights bf16
    float* biasP = (float*)(Wt + 1703936);               // packed biases f32
    float* x2c = u_;                                     // alias (u_ dead after scans)
    unsigned short* hT = (unsigned short*)ws_f;          // [8][4096][1024] bf16, alias wl_

    dim3 blk(256);

    pack_weights<<<dim3(6656), blk, 0, stream>>>(Wu, Ww, Wl, Wo, W1, W2,
                                                 bu, bw, bl, bo, b1, b2, Wt, biasP);
    transpose_to_bf<<<dim3(64, 4, 8), blk, 0, stream>>>(x, xT);

    // u = Wu @ x + bu  (channel-major f32 for scans)
    gemm_mfma<<<dim3(32, 2, 8), blk, 0, stream>>>(xT, Wt, biasP, 256, 256,
                                                  u_, nullptr, nullptr, E_NONE);

    for (int dir = 0; dir < 4; ++dir) {
        // fused taps(768)+lam(256) GEMM; sigmoid on lam rows
        gemm_mfma<<<dim3(32, 8, 8), blk, 0, stream>>>(
            xT, Wt + 65536 + (size_t)dir * 262144, biasP + 256 + dir * 1024,
            256, 1024, wl_, nullptr, nullptr, E_SIG768);
        if (dir < 2)
            scan_dir<<<dim3(512), blk, 0, stream>>>(wl_, wl_ + 3145728, u_, y_,
                                                    dir, dir == 0 ? 1 : 0);
        else
            scan_dir_t<<<dim3(1024), dim3(128), 0, stream>>>(wl_, wl_ + 3145728,
                                                             u_, y_, dir);
    }

    transpose_to_bf<<<dim3(64, 4, 8), blk, 0, stream>>>(y_, yT);

    // x2 = x + Wo @ y + bo : f32 channel-major (x2c) + bf16 pixel-major (x2T)
    gemm_mfma<<<dim3(32, 2, 8), blk, 0, stream>>>(yT, Wt + 1114112, biasP + 4352,
                                                  256, 256, x2c, x2T, x, E_RES);
    // h = gelu(x2 @ W1 + b1) : bf16 pixel-major only
    gemm_mfma<<<dim3(32, 8, 8), blk, 0, stream>>>(x2T, Wt + 1179648, biasP + 4608,
                                                  256, 1024, nullptr, hT, nullptr, E_GELU);
    // out = x2 + h @ W2 + b2 : f32 channel-major = d_out
    gemm_mfma<<<dim3(32, 2, 8), blk, 0, stream>>>(hT, Wt + 1441792, biasP + 5632,
                                                  1024, 256, out, nullptr, x2c, E_RES);
}

// Round 6
// 794.600 us; speedup vs baseline: 5.3758x; 1.0229x over previous
//
#include <hip/hip_runtime.h>
#include <hip/hip_bf16.h>
#include <math.h>

#define HW 4096
#define WD 64
#define CDIM 256
#define BATCH 8
#define CH 16

typedef __attribute__((ext_vector_type(8))) short s16x8;
typedef __attribute__((ext_vector_type(8))) __bf16 b16x8;
typedef __attribute__((ext_vector_type(4))) float f32x4;

enum { E_NONE = 0, E_SIG768 = 1, E_GELU = 2, E_RES = 3 };

__device__ __forceinline__ unsigned short f2bf(float f) {
    union { float f; unsigned u; } v; v.f = f;
    unsigned r = (v.u + 0x7fffu + ((v.u >> 16) & 1u)) >> 16;
    return (unsigned short)r;
}

__device__ __forceinline__ void gload16(const void* g, void* l) {
    __builtin_amdgcn_global_load_lds(
        (const __attribute__((address_space(1))) void*)g,
        (__attribute__((address_space(3))) void*)l, 16, 0, 0);
}

__device__ __forceinline__ f32x4 mfma_bf16(s16x8 a, s16x8 b, f32x4 c) {
    return __builtin_amdgcn_mfma_f32_16x16x32_bf16(
        __builtin_bit_cast(b16x8, a), __builtin_bit_cast(b16x8, b), c, 0, 0, 0);
}

// Pack all weights to bf16 [M][K] row-major blocks + packed bias vector.
// Wt layout (bf16 elems): u@0(64K), dir d@65536+d*262144(4x256K), o@1114112,
// W1t@1179648 (A[m][k]=W1[k][m]), W2t@1441792 (A[m][k]=W2[k][m]).
__global__ __launch_bounds__(256) void pack_weights(
    const float* __restrict__ Wu, const float* __restrict__ Ww,
    const float* __restrict__ Wl, const float* __restrict__ Wo,
    const float* __restrict__ W1, const float* __restrict__ W2,
    const float* __restrict__ bu, const float* __restrict__ bw,
    const float* __restrict__ bl, const float* __restrict__ bo,
    const float* __restrict__ b1, const float* __restrict__ b2,
    unsigned short* __restrict__ Wt, float* __restrict__ biasP)
{
    const int gid = blockIdx.x * 256 + threadIdx.x;
    if (gid < 1703936) {
        float v;
        if (gid < 65536) { v = Wu[gid]; }
        else if (gid < 1114112) {
            int t = gid - 65536; int d = t >> 18; int r = t & 262143;
            int m = r >> 8; int k = r & 255;
            v = (m < 768) ? Ww[(size_t)(d * 768 + m) * 256 + k]
                          : Wl[(size_t)(d * 256 + (m - 768)) * 256 + k];
        }
        else if (gid < 1179648) { v = Wo[gid - 1114112]; }
        else if (gid < 1441792) {
            int t = gid - 1179648; int m = t >> 8; int k = t & 255;
            v = W1[(size_t)k * 1024 + m];
        }
        else {
            int t = gid - 1441792; int m = t >> 10; int k = t & 1023;
            v = W2[(size_t)k * 256 + m];
        }
        Wt[gid] = f2bf(v);
    }
    if (gid < 5888) {
        float v;
        if (gid < 256) v = bu[gid];
        else if (gid < 4352) {
            int t = gid - 256; int d = t >> 10; int r = t & 1023;
            v = (r < 768) ? bw[d * 768 + r] : bl[d * 256 + (r - 768)];
        }
        else if (gid < 4608) v = bo[gid - 4352];
        else if (gid < 5632) v = b1[gid - 4608];
        else v = b2[gid - 5632];
        biasP[gid] = v;
    }
}

// fp32 channel-major [B][256][4096] -> bf16 pixel-major [B][4096][256]
__global__ __launch_bounds__(256) void transpose_to_bf(
    const float* __restrict__ src, unsigned short* __restrict__ dst)
{
    __shared__ float T[64][65];
    const int t = threadIdx.x;
    const int n0 = blockIdx.x * 64, c0 = blockIdx.y * 64, b = blockIdx.z;
    const int nl = t & 63, cg = t >> 6;
#pragma unroll
    for (int i = 0; i < 16; ++i) {
        int cl = cg + i * 4;
        T[cl][nl] = src[((size_t)b * 256 + c0 + cl) * HW + n0 + nl];
    }
    __syncthreads();
#pragma unroll
    for (int i = 0; i < 16; ++i) {
        int nl2 = cg + i * 4;
        dst[((size_t)b * HW + n0 + nl2) * 256 + c0 + (t & 63)] = f2bf(T[t & 63][nl2]);
    }
}

// MFMA GEMM: for each batch b, pixel n, channel m:
//   acc = sum_k Abf[b][n][k] * Wbf[m][k]   (bf16 in, fp32 accum)
//   v = epi(acc + bias[m] [+ resCM])  -> outCM [B][M][4096] f32 and/or
//                                        outPM [B][4096][M] bf16
// 128(pixels) x 128(channels) tile, 4 waves 2x2, 16x16x32 MFMA, BK=32.
// LDS k-chunk XOR swizzle (T2, rule #21): LDS dest linear; global source
// chunk pre-permuted by ((l>>3)&3); reads XOR the same pattern -> the 16
// lanes of a fragment cover all 8 16B slots of the 128B bank cycle evenly.
__global__ __launch_bounds__(256) void gemm_mfma(
    const unsigned short* __restrict__ Abf,
    const unsigned short* __restrict__ Wbf,
    const float* __restrict__ bias,
    int K, int M,
    float* __restrict__ outCM,
    unsigned short* __restrict__ outPM,
    const float* __restrict__ resCM,
    int epi)
{
    __shared__ __align__(16) short At[128 * 32];   // 8 KB, rows = pixels, 32 k
    __shared__ __align__(16) short Bt[128 * 32];   // 8 KB, rows = channels
    const int tid = threadIdx.x;
    const int w = tid >> 6, l = tid & 63;
    const int n0 = blockIdx.x * 128;
    const int m0 = blockIdx.y * 128;
    const int bz = blockIdx.z;
    const int wpi = w >> 1, wcj = w & 1;          // wave 2x2 position
    const int lr = l & 15, lg = l >> 4;           // frag row/col, k-group

    const unsigned short* Ab = Abf + (size_t)bz * HW * K;

    f32x4 acc[4][4];
#pragma unroll
    for (int i = 0; i < 4; ++i)
#pragma unroll
        for (int j = 0; j < 4; ++j) acc[i][j] = (f32x4)0.f;

    // lane k-offset with XOR swizzle: chunk = (l&3) ^ ((l>>3)&3)
    const int sko = (((l & 3) ^ ((l >> 3) & 3)) * 8);
    const int rsw = (lr >> 1) & 3;                // read-side XOR = ((row>>1)&3)
    for (int k0 = 0; k0 < K; k0 += 32) {
#pragma unroll
        for (int cc = 0; cc < 2; ++cc) {
            const int c = w * 2 + cc;             // chunk 0..7, wave-uniform
            const int row = c * 16 + (l >> 2);    // per-lane global row
            gload16(Ab  + (size_t)(n0 + row) * K + k0 + sko, (char*)At + c * 1024);
            gload16(Wbf + (size_t)(m0 + row) * K + k0 + sko, (char*)Bt + c * 1024);
        }
        __syncthreads();                          // drains vmcnt -> LDS ready
        s16x8 av[4], bv[4];
#pragma unroll
        for (int f = 0; f < 4; ++f) {
            av[f] = *(const s16x8*)&At[(wpi * 64 + f * 16 + lr) * 32 + (lg ^ rsw) * 8];
            bv[f] = *(const s16x8*)&Bt[(wcj * 64 + f * 16 + lr) * 32 + (lg ^ rsw) * 8];
        }
#pragma unroll
        for (int fi = 0; fi < 4; ++fi)
#pragma unroll
            for (int fj = 0; fj < 4; ++fj)
                acc[fi][fj] = mfma_bf16(av[fi], bv[fj], acc[fi][fj]);
        __syncthreads();                          // protect LDS reuse
    }

#pragma unroll
    for (int fi = 0; fi < 4; ++fi) {
#pragma unroll
        for (int fj = 0; fj < 4; ++fj) {
            const int m = m0 + wcj * 64 + fj * 16 + lr;
            const float bs = bias[m];
#pragma unroll
            for (int r = 0; r < 4; ++r) {
                const int n = n0 + wpi * 64 + fi * 16 + lg * 4 + r;
                float v = acc[fi][fj][r] + bs;
                if (epi == E_SIG768)      { if (m >= 768) v = 1.f / (1.f + expf(-v)); }
                else if (epi == E_GELU)   v = 0.5f * v * (1.f + erff(v * 0.70710678118654752f));
                else if (epi == E_RES)    v += resCM[((size_t)bz * M + m) * HW + n];
                if (outCM) outCM[((size_t)bz * M + m) * HW + n] = v;
                if (outPM) outPM[((size_t)bz * HW + n) * M + m] = f2bf(v);
            }
        }
    }
}

// Row-direction scans (dirs 0/1). w3/lam live in wl_ ([B][1024][HW] f32):
// per-batch stride 1024*HW for w3/lam, 256*HW for u/y. lam ptr pre-offset.
__global__ __launch_bounds__(256) void scan_dir(
    const float* __restrict__ w3,
    const float* __restrict__ lam,
    const float* __restrict__ u,
    float* __restrict__ y,
    int dir, int overwrite)
{
    const int wave = threadIdx.x >> 6;
    const int lane = threadIdx.x & 63;
    const int plane = blockIdx.x * 4 + wave;
    const int b = plane >> 8;
    const int c = plane & 255;

    const size_t base_w = (size_t)b * (1024 * HW) + (size_t)c * HW;
    const size_t base_u = ((size_t)b * CDIM + c) * HW;
    const size_t tapstr = (size_t)CDIM * HW;

    float h = 0.f;
    for (int s = 0; s < 64; ++s) {
        const int p = (dir == 1) ? (63 - s) : s;
        const size_t off = (size_t)p * WD + lane;
        float w0 = w3[base_w + off];
        float w1 = w3[base_w + tapstr + off];
        float w2 = w3[base_w + 2 * tapstr + off];
        float dn = 1.0f / (fabsf(w0) + fabsf(w1) + fabsf(w2) + 1e-6f);
        float lm = lam[base_w + off];
        float uu = u[base_u + off];

        float hl = __shfl_up(h, 1);
        float hr = __shfl_down(h, 1);
        if (lane == 0)  hl = 0.f;
        if (lane == 63) hr = 0.f;

        h = (w0 * hl + w1 * h + w2 * hr) * dn + lm * uu;

        if (overwrite) y[base_u + off] = h;
        else           y[base_u + off] += h;
    }
}

// Column-direction scans (dirs 2/3), LDS-tiled (validated round 1/4).
__global__ __launch_bounds__(128) void scan_dir_t(
    const float* __restrict__ w3,
    const float* __restrict__ lam,
    const float* __restrict__ u,
    float* __restrict__ y,
    int dir)
{
    __shared__ float T[2][5][64][CH + 1];
    const int wv = threadIdx.x >> 6;
    const int lane = threadIdx.x & 63;
    const int plane = blockIdx.x * 2 + wv;
    const int b = plane >> 8;
    const int c = plane & 255;

    const size_t base_w = (size_t)b * (1024 * HW) + (size_t)c * HW;
    const size_t base_u = ((size_t)b * CDIM + c) * HW;
    const size_t tapstr = (size_t)CDIM * HW;
    const int rr = lane >> 2;
    const int q  = lane & 3;

    const float* srcs[5];
    srcs[0] = w3 + base_w;
    srcs[1] = w3 + base_w + tapstr;
    srcs[2] = w3 + base_w + 2 * tapstr;
    srcs[3] = lam + base_w;
    srcs[4] = u + base_u;

    float h = 0.f;
    for (int ci = 0; ci < 4; ++ci) {
        const int p0 = (dir == 3) ? (48 - ci * 16) : (ci * 16);
#pragma unroll
        for (int a = 0; a < 5; ++a) {
            const float* s = srcs[a];
#pragma unroll
            for (int i = 0; i < 4; ++i) {
                const int r = i * 16 + rr;
                const float4 v = *(const float4*)(s + (size_t)r * WD + p0 + q * 4);
                T[wv][a][r][q * 4 + 0] = v.x;
                T[wv][a][r][q * 4 + 1] = v.y;
                T[wv][a][r][q * 4 + 2] = v.z;
                T[wv][a][r][q * 4 + 3] = v.w;
            }
        }
        for (int t = 0; t < CH; ++t) {
            const int pp = (dir == 3) ? (CH - 1 - t) : t;
            float w0 = T[wv][0][lane][pp];
            float w1 = T[wv][1][lane][pp];
            float w2 = T[wv][2][lane][pp];
            float dn = 1.0f / (fabsf(w0) + fabsf(w1) + fabsf(w2) + 1e-6f);
            float lm = T[wv][3][lane][pp];
            float uu = T[wv][4][lane][pp];

            float hl = __shfl_up(h, 1);
            float hr = __shfl_down(h, 1);
            if (lane == 0)  hl = 0.f;
            if (lane == 63) hr = 0.f;

            h = (w0 * hl + w1 * h + w2 * hr) * dn + lm * uu;
            T[wv][4][lane][pp] = h;
        }
#pragma unroll
        for (int i = 0; i < 4; ++i) {
            const int r = i * 16 + rr;
            const size_t g = base_u + (size_t)r * WD + p0 + q * 4;
            float4 old = *(const float4*)(y + g);
            old.x += T[wv][4][r][q * 4 + 0];
            old.y += T[wv][4][r][q * 4 + 1];
            old.z += T[wv][4][r][q * 4 + 2];
            old.w += T[wv][4][r][q * 4 + 3];
            *(float4*)(y + g) = old;
        }
    }
}

extern "C" void kernel_launch(void* const* d_in, const int* in_sizes, int n_in,
                              void* d_out, int out_size, void* d_ws, size_t ws_size,
                              hipStream_t stream)
{
    const float* x  = (const float*)d_in[0];
    const float* Wu = (const float*)d_in[1];
    const float* bu = (const float*)d_in[2];
    const float* Ww = (const float*)d_in[3];
    const float* bw = (const float*)d_in[4];
    const float* Wl = (const float*)d_in[5];
    const float* bl = (const float*)d_in[6];
    const float* Wo = (const float*)d_in[7];
    const float* bo = (const float*)d_in[8];
    const float* W1 = (const float*)d_in[9];
    const float* b1 = (const float*)d_in[10];
    const float* W2 = (const float*)d_in[11];
    const float* b2 = (const float*)d_in[12];
    float* out = (float*)d_out;

    // ws layout (255.1 MB total; 268 MB proven available in round 1):
    float* ws_f = (float*)d_ws;
    float* wl_  = ws_f;                                  // [8][1024][4096] f32 (taps+lam per dir)
    float* u_   = ws_f + 33554432;                       // [8][256][4096] f32; later x2c
    float* y_   = u_ + 8388608;                          // [8][256][4096] f32
    unsigned short* xT  = (unsigned short*)(y_ + 8388608);  // [8][4096][256] bf16
    unsigned short* yT  = xT + 8388608;
    unsigned short* x2T = yT + 8388608;
    unsigned short* Wt  = x2T + 8388608;                 // packed weights bf16
    float* biasP = (float*)(Wt + 1703936);               // packed biases f32
    float* x2c = u_;                                     // alias (u_ dead after scans)
    unsigned short* hT = (unsigned short*)ws_f;          // [8][4096][1024] bf16, alias wl_

    dim3 blk(256);

    pack_weights<<<dim3(6656), blk, 0, stream>>>(Wu, Ww, Wl, Wo, W1, W2,
                                                 bu, bw, bl, bo, b1, b2, Wt, biasP);
    transpose_to_bf<<<dim3(64, 4, 8), blk, 0, stream>>>(x, xT);

    // u = Wu @ x + bu  (channel-major f32 for scans)
    gemm_mfma<<<dim3(32, 2, 8), blk, 0, stream>>>(xT, Wt, biasP, 256, 256,
                                                  u_, nullptr, nullptr, E_NONE);

    for (int dir = 0; dir < 4; ++dir) {
        // fused taps(768)+lam(256) GEMM; sigmoid on lam rows
        gemm_mfma<<<dim3(32, 8, 8), blk, 0, stream>>>(
            xT, Wt + 65536 + (size_t)dir * 262144, biasP + 256 + dir * 1024,
            256, 1024, wl_, nullptr, nullptr, E_SIG768);
        if (dir < 2)
            scan_dir<<<dim3(512), blk, 0, stream>>>(wl_, wl_ + 3145728, u_, y_,
                                                    dir, dir == 0 ? 1 : 0);
        else
            scan_dir_t<<<dim3(1024), dim3(128), 0, stream>>>(wl_, wl_ + 3145728,
                                                             u_, y_, dir);
    }

    transpose_to_bf<<<dim3(64, 4, 8), blk, 0, stream>>>(y_, yT);

    // x2 = x + Wo @ y + bo : f32 channel-major (x2c) + bf16 pixel-major (x2T)
    gemm_mfma<<<dim3(32, 2, 8), blk, 0, stream>>>(yT, Wt + 1114112, biasP + 4352,
                                                  256, 256, x2c, x2T, x, E_RES);
    // h = gelu(x2 @ W1 + b1) : bf16 pixel-major only
    gemm_mfma<<<dim3(32, 8, 8), blk, 0, stream>>>(x2T, Wt + 1179648, biasP + 4608,
                                                  256, 1024, nullptr, hT, nullptr, E_GELU);
    // out = x2 + h @ W2 + b2 : f32 channel-major = d_out
    gemm_mfma<<<dim3(32, 2, 8), blk, 0, stream>>>(hT, Wt + 1441792, biasP + 5632,
                                                  1024, 256, out, nullptr, x2c, E_RES);
}

// Round 7
// 785.221 us; speedup vs baseline: 5.4400x; 1.0119x over previous
//
#include <hip/hip_runtime.h>
#include <hip/hip_bf16.h>
#include <math.h>

#define HW 4096
#define WD 64
#define CDIM 256
#define BATCH 8
#define CH 16

typedef __attribute__((ext_vector_type(8))) short s16x8;
typedef __attribute__((ext_vector_type(8))) __bf16 b16x8;
typedef __attribute__((ext_vector_type(4))) float f32x4;

enum { E_NONE = 0, E_SIG768 = 1, E_GELU = 2, E_RES = 3 };

__device__ __forceinline__ unsigned short f2bf(float f) {
    union { float f; unsigned u; } v; v.f = f;
    unsigned r = (v.u + 0x7fffu + ((v.u >> 16) & 1u)) >> 16;
    return (unsigned short)r;
}
__device__ __forceinline__ float bf2f(unsigned short h) {
    union { unsigned u; float f; } v; v.u = ((unsigned)h) << 16; return v.f;
}

__device__ __forceinline__ void gload16(const void* g, void* l) {
    __builtin_amdgcn_global_load_lds(
        (const __attribute__((address_space(1))) void*)g,
        (__attribute__((address_space(3))) void*)l, 16, 0, 0);
}

__device__ __forceinline__ f32x4 mfma_bf16(s16x8 a, s16x8 b, f32x4 c) {
    return __builtin_amdgcn_mfma_f32_16x16x32_bf16(
        __builtin_bit_cast(b16x8, a), __builtin_bit_cast(b16x8, b), c, 0, 0, 0);
}

// Pack all weights to bf16 [M][K] row-major blocks + packed bias vector.
__global__ __launch_bounds__(256) void pack_weights(
    const float* __restrict__ Wu, const float* __restrict__ Ww,
    const float* __restrict__ Wl, const float* __restrict__ Wo,
    const float* __restrict__ W1, const float* __restrict__ W2,
    const float* __restrict__ bu, const float* __restrict__ bw,
    const float* __restrict__ bl, const float* __restrict__ bo,
    const float* __restrict__ b1, const float* __restrict__ b2,
    unsigned short* __restrict__ Wt, float* __restrict__ biasP)
{
    const int gid = blockIdx.x * 256 + threadIdx.x;
    if (gid < 1703936) {
        float v;
        if (gid < 65536) { v = Wu[gid]; }
        else if (gid < 1114112) {
            int t = gid - 65536; int d = t >> 18; int r = t & 262143;
            int m = r >> 8; int k = r & 255;
            v = (m < 768) ? Ww[(size_t)(d * 768 + m) * 256 + k]
                          : Wl[(size_t)(d * 256 + (m - 768)) * 256 + k];
        }
        else if (gid < 1179648) { v = Wo[gid - 1114112]; }
        else if (gid < 1441792) {
            int t = gid - 1179648; int m = t >> 8; int k = t & 255;
            v = W1[(size_t)k * 1024 + m];
        }
        else {
            int t = gid - 1441792; int m = t >> 10; int k = t & 1023;
            v = W2[(size_t)k * 256 + m];
        }
        Wt[gid] = f2bf(v);
    }
    if (gid < 5888) {
        float v;
        if (gid < 256) v = bu[gid];
        else if (gid < 4352) {
            int t = gid - 256; int d = t >> 10; int r = t & 1023;
            v = (r < 768) ? bw[d * 768 + r] : bl[d * 256 + (r - 768)];
        }
        else if (gid < 4608) v = bo[gid - 4352];
        else if (gid < 5632) v = b1[gid - 4608];
        else v = b2[gid - 5632];
        biasP[gid] = v;
    }
}

// fp32 channel-major [B][256][4096] -> bf16 pixel-major [B][4096][256]
__global__ __launch_bounds__(256) void transpose_to_bf(
    const float* __restrict__ src, unsigned short* __restrict__ dst)
{
    __shared__ float T[64][65];
    const int t = threadIdx.x;
    const int n0 = blockIdx.x * 64, c0 = blockIdx.y * 64, b = blockIdx.z;
    const int nl = t & 63, cg = t >> 6;
#pragma unroll
    for (int i = 0; i < 16; ++i) {
        int cl = cg + i * 4;
        T[cl][nl] = src[((size_t)b * 256 + c0 + cl) * HW + n0 + nl];
    }
    __syncthreads();
#pragma unroll
    for (int i = 0; i < 16; ++i) {
        int nl2 = cg + i * 4;
        dst[((size_t)b * HW + n0 + nl2) * 256 + c0 + (t & 63)] = f2bf(T[t & 63][nl2]);
    }
}

// MFMA GEMM, 128x128 tile, 4 waves 2x2, 16x16x32, BK=32.
// 2-phase prefetch (T3-minimum): double-buffered LDS, stage K-step t+1
// before computing step t, ONE __syncthreads per step (its vmcnt(0) drain
// is the handoff). k-chunk XOR swizzle kept (conflicts = 0, validated r6).
__global__ __launch_bounds__(256) void gemm_mfma(
    const unsigned short* __restrict__ Abf,
    const unsigned short* __restrict__ Wbf,
    const float* __restrict__ bias,
    int K, int M,
    float* __restrict__ outCM,
    unsigned short* __restrict__ outCMh,
    unsigned short* __restrict__ outPM,
    const float* __restrict__ resCM,
    int epi)
{
    __shared__ __align__(16) short At[2][128 * 32];   // 16 KB
    __shared__ __align__(16) short Bt[2][128 * 32];   // 16 KB
    const int tid = threadIdx.x;
    const int w = tid >> 6, l = tid & 63;
    const int n0 = blockIdx.x * 128;
    const int m0 = blockIdx.y * 128;
    const int bz = blockIdx.z;
    const int wpi = w >> 1, wcj = w & 1;
    const int lr = l & 15, lg = l >> 4;

    const unsigned short* Ab = Abf + (size_t)bz * HW * K;

    f32x4 acc[4][4];
#pragma unroll
    for (int i = 0; i < 4; ++i)
#pragma unroll
        for (int j = 0; j < 4; ++j) acc[i][j] = (f32x4)0.f;

    // lane k-offset with XOR swizzle: chunk = (l&3) ^ ((l>>3)&3)
    const int sko = (((l & 3) ^ ((l >> 3) & 3)) * 8);
    const int rsw = (lr >> 1) & 3;                // read-side XOR
    const int row_l = (l >> 2);

#define STAGE(buf, kk)                                                         \
    {                                                                          \
        _Pragma("unroll")                                                      \
        for (int cc = 0; cc < 2; ++cc) {                                       \
            const int c = w * 2 + cc;                                          \
            const int row = c * 16 + row_l;                                    \
            gload16(Ab  + (size_t)(n0 + row) * K + (kk) + sko,                 \
                    (char*)&At[buf][0] + c * 1024);                            \
            gload16(Wbf + (size_t)(m0 + row) * K + (kk) + sko,                 \
                    (char*)&Bt[buf][0] + c * 1024);                            \
        }                                                                      \
    }

    STAGE(0, 0);
    int cur = 0;
    for (int k0 = 0; k0 < K; k0 += 32) {
        __syncthreads();                          // buf[cur] ready (vmcnt drain)
        if (k0 + 32 < K) STAGE(cur ^ 1, k0 + 32);
        s16x8 av[4], bv[4];
#pragma unroll
        for (int f = 0; f < 4; ++f) {
            av[f] = *(const s16x8*)&At[cur][(wpi * 64 + f * 16 + lr) * 32 + (lg ^ rsw) * 8];
            bv[f] = *(const s16x8*)&Bt[cur][(wcj * 64 + f * 16 + lr) * 32 + (lg ^ rsw) * 8];
        }
#pragma unroll
        for (int fi = 0; fi < 4; ++fi)
#pragma unroll
            for (int fj = 0; fj < 4; ++fj)
                acc[fi][fj] = mfma_bf16(av[fi], bv[fj], acc[fi][fj]);
        cur ^= 1;
    }
#undef STAGE

#pragma unroll
    for (int fi = 0; fi < 4; ++fi) {
#pragma unroll
        for (int fj = 0; fj < 4; ++fj) {
            const int m = m0 + wcj * 64 + fj * 16 + lr;
            const float bs = bias[m];
#pragma unroll
            for (int r = 0; r < 4; ++r) {
                const int n = n0 + wpi * 64 + fi * 16 + lg * 4 + r;
                float v = acc[fi][fj][r] + bs;
                if (epi == E_SIG768)      { if (m >= 768) v = 1.f / (1.f + expf(-v)); }
                else if (epi == E_GELU)   v = 0.5f * v * (1.f + erff(v * 0.70710678118654752f));
                else if (epi == E_RES)    v += resCM[((size_t)bz * M + m) * HW + n];
                const size_t o = ((size_t)bz * M + m) * HW + n;
                if (outCM)  outCM[o] = v;
                if (outCMh) outCMh[o] = f2bf(v);
                if (outPM)  outPM[((size_t)bz * HW + n) * M + m] = f2bf(v);
            }
        }
    }
}

// Row-direction scans (dirs 0/1). Taps+lam are bf16 [B][1024][HW]; u,y f32.
__global__ __launch_bounds__(256) void scan_dir(
    const unsigned short* __restrict__ w3,
    const unsigned short* __restrict__ lam,
    const float* __restrict__ u,
    float* __restrict__ y,
    int dir, int overwrite)
{
    const int wave = threadIdx.x >> 6;
    const int lane = threadIdx.x & 63;
    const int plane = blockIdx.x * 4 + wave;
    const int b = plane >> 8;
    const int c = plane & 255;

    const size_t base_w = (size_t)b * (1024 * HW) + (size_t)c * HW;
    const size_t base_u = ((size_t)b * CDIM + c) * HW;
    const size_t tapstr = (size_t)CDIM * HW;

    float h = 0.f;
    for (int s = 0; s < 64; ++s) {
        const int p = (dir == 1) ? (63 - s) : s;
        const size_t off = (size_t)p * WD + lane;
        float w0 = bf2f(w3[base_w + off]);
        float w1 = bf2f(w3[base_w + tapstr + off]);
        float w2 = bf2f(w3[base_w + 2 * tapstr + off]);
        float dn = 1.0f / (fabsf(w0) + fabsf(w1) + fabsf(w2) + 1e-6f);
        float lm = bf2f(lam[base_w + off]);
        float uu = u[base_u + off];

        float hl = __shfl_up(h, 1);
        float hr = __shfl_down(h, 1);
        if (lane == 0)  hl = 0.f;
        if (lane == 63) hr = 0.f;

        h = (w0 * hl + w1 * h + w2 * hr) * dn + lm * uu;

        if (overwrite) y[base_u + off] = h;
        else           y[base_u + off] += h;
    }
}

// Column-direction scans (dirs 2/3), LDS-tiled. Taps/lam bf16, u/y f32.
__global__ __launch_bounds__(128) void scan_dir_t(
    const unsigned short* __restrict__ w3,
    const unsigned short* __restrict__ lam,
    const float* __restrict__ u,
    float* __restrict__ y,
    int dir)
{
    __shared__ float T[2][5][64][CH + 1];
    const int wv = threadIdx.x >> 6;
    const int lane = threadIdx.x & 63;
    const int plane = blockIdx.x * 2 + wv;
    const int b = plane >> 8;
    const int c = plane & 255;

    const size_t base_w = (size_t)b * (1024 * HW) + (size_t)c * HW;
    const size_t base_u = ((size_t)b * CDIM + c) * HW;
    const size_t tapstr = (size_t)CDIM * HW;
    const int rr = lane >> 2;
    const int q  = lane & 3;

    const unsigned short* hsrc[4];
    hsrc[0] = w3 + base_w;
    hsrc[1] = w3 + base_w + tapstr;
    hsrc[2] = w3 + base_w + 2 * tapstr;
    hsrc[3] = lam + base_w;

    float h = 0.f;
    for (int ci = 0; ci < 4; ++ci) {
        const int p0 = (dir == 3) ? (48 - ci * 16) : (ci * 16);
#pragma unroll
        for (int a = 0; a < 4; ++a) {
            const unsigned short* s = hsrc[a];
#pragma unroll
            for (int i = 0; i < 4; ++i) {
                const int r = i * 16 + rr;
                const ushort4 v = *(const ushort4*)(s + (size_t)r * WD + p0 + q * 4);
                T[wv][a][r][q * 4 + 0] = bf2f(v.x);
                T[wv][a][r][q * 4 + 1] = bf2f(v.y);
                T[wv][a][r][q * 4 + 2] = bf2f(v.z);
                T[wv][a][r][q * 4 + 3] = bf2f(v.w);
            }
        }
#pragma unroll
        for (int i = 0; i < 4; ++i) {
            const int r = i * 16 + rr;
            const float4 v = *(const float4*)(u + base_u + (size_t)r * WD + p0 + q * 4);
            T[wv][4][r][q * 4 + 0] = v.x;
            T[wv][4][r][q * 4 + 1] = v.y;
            T[wv][4][r][q * 4 + 2] = v.z;
            T[wv][4][r][q * 4 + 3] = v.w;
        }
        for (int t = 0; t < CH; ++t) {
            const int pp = (dir == 3) ? (CH - 1 - t) : t;
            float w0 = T[wv][0][lane][pp];
            float w1 = T[wv][1][lane][pp];
            float w2 = T[wv][2][lane][pp];
            float dn = 1.0f / (fabsf(w0) + fabsf(w1) + fabsf(w2) + 1e-6f);
            float lm = T[wv][3][lane][pp];
            float uu = T[wv][4][lane][pp];

            float hl = __shfl_up(h, 1);
            float hr = __shfl_down(h, 1);
            if (lane == 0)  hl = 0.f;
            if (lane == 63) hr = 0.f;

            h = (w0 * hl + w1 * h + w2 * hr) * dn + lm * uu;
            T[wv][4][lane][pp] = h;
        }
#pragma unroll
        for (int i = 0; i < 4; ++i) {
            const int r = i * 16 + rr;
            const size_t g = base_u + (size_t)r * WD + p0 + q * 4;
            float4 old = *(const float4*)(y + g);
            old.x += T[wv][4][r][q * 4 + 0];
            old.y += T[wv][4][r][q * 4 + 1];
            old.z += T[wv][4][r][q * 4 + 2];
            old.w += T[wv][4][r][q * 4 + 3];
            *(float4*)(y + g) = old;
        }
    }
}

extern "C" void kernel_launch(void* const* d_in, const int* in_sizes, int n_in,
                              void* d_out, int out_size, void* d_ws, size_t ws_size,
                              hipStream_t stream)
{
    const float* x  = (const float*)d_in[0];
    const float* Wu = (const float*)d_in[1];
    const float* bu = (const float*)d_in[2];
    const float* Ww = (const float*)d_in[3];
    const float* bw = (const float*)d_in[4];
    const float* Wl = (const float*)d_in[5];
    const float* bl = (const float*)d_in[6];
    const float* Wo = (const float*)d_in[7];
    const float* bo = (const float*)d_in[8];
    const float* W1 = (const float*)d_in[9];
    const float* b1 = (const float*)d_in[10];
    const float* W2 = (const float*)d_in[11];
    const float* b2 = (const float*)d_in[12];
    float* out = (float*)d_out;

    // ws layout (~188 MB; >=255 MB proven available):
    unsigned short* wlh = (unsigned short*)d_ws;            // [8][1024][4096] bf16 taps+lam
    float* u_  = (float*)(wlh + 33554432);                  // [8][256][4096] f32; later x2c
    float* y_  = u_ + 8388608;                              // [8][256][4096] f32
    unsigned short* xT  = (unsigned short*)(y_ + 8388608);  // [8][4096][256] bf16
    unsigned short* yT  = xT + 8388608;
    unsigned short* x2T = yT + 8388608;
    unsigned short* Wt  = x2T + 8388608;
    float* biasP = (float*)(Wt + 1703936);
    float* x2c = u_;                                        // alias (u_ dead after scans)
    unsigned short* hT = wlh;                               // [8][4096][1024] bf16, alias

    dim3 blk(256);

    pack_weights<<<dim3(6656), blk, 0, stream>>>(Wu, Ww, Wl, Wo, W1, W2,
                                                 bu, bw, bl, bo, b1, b2, Wt, biasP);
    transpose_to_bf<<<dim3(64, 4, 8), blk, 0, stream>>>(x, xT);

    // u = Wu @ x + bu  (f32 channel-major for scans)
    gemm_mfma<<<dim3(32, 2, 8), blk, 0, stream>>>(xT, Wt, biasP, 256, 256,
                                                  u_, nullptr, nullptr, nullptr, E_NONE);

    for (int dir = 0; dir < 4; ++dir) {
        // fused taps(768)+lam(256) GEMM -> bf16 channel-major; sigmoid on lam rows
        gemm_mfma<<<dim3(32, 8, 8), blk, 0, stream>>>(
            xT, Wt + 65536 + (size_t)dir * 262144, biasP + 256 + dir * 1024,
            256, 1024, nullptr, wlh, nullptr, nullptr, E_SIG768);
        if (dir < 2)
            scan_dir<<<dim3(512), blk, 0, stream>>>(wlh, wlh + 3145728, u_, y_,
                                                    dir, dir == 0 ? 1 : 0);
        else
            scan_dir_t<<<dim3(1024), dim3(128), 0, stream>>>(wlh, wlh + 3145728,
                                                             u_, y_, dir);
    }

    transpose_to_bf<<<dim3(64, 4, 8), blk, 0, stream>>>(y_, yT);

    // x2 = x + Wo @ y + bo : f32 CM (x2c) + bf16 PM (x2T)
    gemm_mfma<<<dim3(32, 2, 8), blk, 0, stream>>>(yT, Wt + 1114112, biasP + 4352,
                                                  256, 256, x2c, nullptr, x2T, x, E_RES);
    // h = gelu(x2 @ W1 + b1) : bf16 PM only
    gemm_mfma<<<dim3(32, 8, 8), blk, 0, stream>>>(x2T, Wt + 1179648, biasP + 4608,
                                                  256, 1024, nullptr, nullptr, hT, nullptr, E_GELU);
    // out = x2 + h @ W2 + b2 : f32 CM = d_out
    gemm_mfma<<<dim3(32, 2, 8), blk, 0, stream>>>(hT, Wt + 1441792, biasP + 5632,
                                                  1024, 256, out, nullptr, nullptr, x2c, E_RES);
}

// Round 9
// 532.866 us; speedup vs baseline: 8.0163x; 1.4736x over previous
//
#include <hip/hip_runtime.h>
#include <hip/hip_bf16.h>
#include <math.h>

#define HW 4096
#define WD 64
#define CDIM 256
#define BATCH 8
#define CH 16

typedef __attribute__((ext_vector_type(8))) short s16x8;
typedef __attribute__((ext_vector_type(8))) __bf16 b16x8;
typedef __attribute__((ext_vector_type(4))) float f32x4;
typedef __attribute__((ext_vector_type(8))) unsigned short us16x8;

enum { E_NONE = 0, E_SIG768 = 1, E_GELU = 2, E_RES = 3 };

__device__ __forceinline__ unsigned short f2bf(float f) {
    union { float f; unsigned u; } v; v.f = f;
    unsigned r = (v.u + 0x7fffu + ((v.u >> 16) & 1u)) >> 16;
    return (unsigned short)r;
}
__device__ __forceinline__ float bf2f(unsigned short h) {
    union { unsigned u; float f; } v; v.u = ((unsigned)h) << 16; return v.f;
}

__device__ __forceinline__ void gload16(const void* g, void* l) {
    __builtin_amdgcn_global_load_lds(
        (const __attribute__((address_space(1))) void*)g,
        (__attribute__((address_space(3))) void*)l, 16, 0, 0);
}

__device__ __forceinline__ f32x4 mfma_bf16(s16x8 a, s16x8 b, f32x4 c) {
    return __builtin_amdgcn_mfma_f32_16x16x32_bf16(
        __builtin_bit_cast(b16x8, a), __builtin_bit_cast(b16x8, b), c, 0, 0, 0);
}

// Pack all weights to bf16 [M][K] row-major blocks + packed bias vector.
__global__ __launch_bounds__(256) void pack_weights(
    const float* __restrict__ Wu, const float* __restrict__ Ww,
    const float* __restrict__ Wl, const float* __restrict__ Wo,
    const float* __restrict__ W1, const float* __restrict__ W2,
    const float* __restrict__ bu, const float* __restrict__ bw,
    const float* __restrict__ bl, const float* __restrict__ bo,
    const float* __restrict__ b1, const float* __restrict__ b2,
    unsigned short* __restrict__ Wt, float* __restrict__ biasP)
{
    const int gid = blockIdx.x * 256 + threadIdx.x;
    if (gid < 1703936) {
        float v;
        if (gid < 65536) { v = Wu[gid]; }
        else if (gid < 1114112) {
            int t = gid - 65536; int d = t >> 18; int r = t & 262143;
            int m = r >> 8; int k = r & 255;
            v = (m < 768) ? Ww[(size_t)(d * 768 + m) * 256 + k]
                          : Wl[(size_t)(d * 256 + (m - 768)) * 256 + k];
        }
        else if (gid < 1179648) { v = Wo[gid - 1114112]; }
        else if (gid < 1441792) {
            int t = gid - 1179648; int m = t >> 8; int k = t & 255;
            v = W1[(size_t)k * 1024 + m];
        }
        else {
            int t = gid - 1441792; int m = t >> 10; int k = t & 1023;
            v = W2[(size_t)k * 256 + m];
        }
        Wt[gid] = f2bf(v);
    }
    if (gid < 5888) {
        float v;
        if (gid < 256) v = bu[gid];
        else if (gid < 4352) {
            int t = gid - 256; int d = t >> 10; int r = t & 1023;
            v = (r < 768) ? bw[d * 768 + r] : bl[d * 256 + (r - 768)];
        }
        else if (gid < 4608) v = bo[gid - 4352];
        else if (gid < 5632) v = b1[gid - 4608];
        else v = b2[gid - 5632];
        biasP[gid] = v;
    }
}

// fp32 channel-major [B][256][4096] -> bf16 pixel-major [B][4096][256]
__global__ __launch_bounds__(256) void transpose_to_bf(
    const float* __restrict__ src, unsigned short* __restrict__ dst)
{
    __shared__ float T[64][65];
    const int t = threadIdx.x;
    const int n0 = blockIdx.x * 64, c0 = blockIdx.y * 64, b = blockIdx.z;
    const int nl = t & 63, cg = t >> 6;
#pragma unroll
    for (int i = 0; i < 16; ++i) {
        int cl = cg + i * 4;
        T[cl][nl] = src[((size_t)b * 256 + c0 + cl) * HW + n0 + nl];
    }
    __syncthreads();
#pragma unroll
    for (int i = 0; i < 16; ++i) {
        int nl2 = cg + i * 4;
        dst[((size_t)b * HW + n0 + nl2) * 256 + c0 + (t & 63)] = f2bf(T[t & 63][nl2]);
    }
}

// MFMA GEMM, 128x128 tile, 4 waves 2x2, 16x16x32, BK=32.
// T4 counted-vmcnt pipeline, depth 2: 3 LDS buffers; per iteration t:
//   [s_waitcnt vmcnt(4); s_barrier]  (drains stage t, keeps t+1 in flight)
//   STAGE(t+2)                       (safe: buf (t+2)%3 last read at t-1,
//                                     separated by the barrier just passed)
//   ds_read buf t, 16 MFMA
// Last iteration waits vmcnt(0). k-chunk XOR swizzle kept (0 conflicts, r6).
// Epilogue: float4 CM-f32 / ushort4 CM-bf16 stores; PM via LDS repack
// (reuses staging SMEM after the loop).
__global__ __launch_bounds__(256) void gemm_mfma(
    const unsigned short* __restrict__ Abf,
    const unsigned short* __restrict__ Wbf,
    const float* __restrict__ bias,
    int K, int M,
    float* __restrict__ outCM,
    unsigned short* __restrict__ outCMh,
    unsigned short* __restrict__ outPM,
    const float* __restrict__ resCM,
    int epi)
{
    __shared__ __align__(16) char SMEM[49152];     // 3 bufs x (A 8KB + B 8KB)
    const int tid = threadIdx.x;
    const int w = tid >> 6, l = tid & 63;
    const int n0 = blockIdx.x * 128;
    const int m0 = blockIdx.y * 128;
    const int bz = blockIdx.z;
    const int wpi = w >> 1, wcj = w & 1;
    const int lr = l & 15, lg = l >> 4;

    const unsigned short* Ab = Abf + (size_t)bz * HW * K;

    f32x4 acc[4][4];
#pragma unroll
    for (int i = 0; i < 4; ++i)
#pragma unroll
        for (int j = 0; j < 4; ++j) acc[i][j] = (f32x4)0.f;

    const int sko = (((l & 3) ^ ((l >> 3) & 3)) * 8);   // swizzled k-chunk (elems)
    const int rsw = (lr >> 1) & 3;                      // read-side XOR
    const int row_l = (l >> 2);

#define STAGE(buf, kk)                                                         \
    {                                                                          \
        _Pragma("unroll")                                                      \
        for (int cc = 0; cc < 2; ++cc) {                                       \
            const int c = w * 2 + cc;                                          \
            const int row = c * 16 + row_l;                                    \
            gload16(Ab  + (size_t)(n0 + row) * K + (kk) + sko,                 \
                    SMEM + (buf) * 16384 + c * 1024);                          \
            gload16(Wbf + (size_t)(m0 + row) * K + (kk) + sko,                 \
                    SMEM + (buf) * 16384 + 8192 + c * 1024);                   \
        }                                                                      \
    }

    const int NS = K >> 5;
    STAGE(0, 0);
    if (NS > 1) STAGE(1, 32);
    int cur = 0;
    for (int t = 0; t < NS; ++t) {
        if (t + 1 < NS) asm volatile("s_waitcnt vmcnt(4)\n\ts_barrier" ::: "memory");
        else            asm volatile("s_waitcnt vmcnt(0)\n\ts_barrier" ::: "memory");
        if (t + 2 < NS) {
            int nb = cur + 2; if (nb >= 3) nb -= 3;
            STAGE(nb, (t + 2) * 32);
        }
        const short* Ac = (const short*)(SMEM + cur * 16384);
        const short* Bc = (const short*)(SMEM + cur * 16384 + 8192);
        s16x8 av[4], bv[4];
#pragma unroll
        for (int f = 0; f < 4; ++f) {
            av[f] = *(const s16x8*)&Ac[(wpi * 64 + f * 16 + lr) * 32 + (lg ^ rsw) * 8];
            bv[f] = *(const s16x8*)&Bc[(wcj * 64 + f * 16 + lr) * 32 + (lg ^ rsw) * 8];
        }
#pragma unroll
        for (int fi = 0; fi < 4; ++fi)
#pragma unroll
            for (int fj = 0; fj < 4; ++fj)
                acc[fi][fj] = mfma_bf16(av[fi], bv[fj], acc[fi][fj]);
        if (++cur == 3) cur = 0;
    }
#undef STAGE

    unsigned short* RP = (unsigned short*)SMEM;    // 128x128 bf16 PM repack
    if (outPM) __syncthreads();                    // protect SMEM reuse

#pragma unroll
    for (int fi = 0; fi < 4; ++fi) {
#pragma unroll
        for (int fj = 0; fj < 4; ++fj) {
            const int m = m0 + wcj * 64 + fj * 16 + lr;
            const int nl = wpi * 64 + fi * 16 + lg * 4;   // tile-local n base
            const float bs = bias[m];
            const size_t oc = ((size_t)bz * M + m) * HW + n0 + nl;
            float4 v4;
            float* vp = &v4.x;
#pragma unroll
            for (int r = 0; r < 4; ++r) vp[r] = acc[fi][fj][r] + bs;
            if (epi == E_SIG768) {
                if (m >= 768)
#pragma unroll
                    for (int r = 0; r < 4; ++r) vp[r] = 1.f / (1.f + expf(-vp[r]));
            } else if (epi == E_GELU) {
#pragma unroll
                for (int r = 0; r < 4; ++r)
                    vp[r] = 0.5f * vp[r] * (1.f + erff(vp[r] * 0.70710678118654752f));
            } else if (epi == E_RES) {
                const float4 rv = *(const float4*)&resCM[oc];
                v4.x += rv.x; v4.y += rv.y; v4.z += rv.z; v4.w += rv.w;
            }
            if (outCM)  *(float4*)&outCM[oc] = v4;
            if (outCMh) {
                ushort4 h4 = { f2bf(v4.x), f2bf(v4.y), f2bf(v4.z), f2bf(v4.w) };
                *(ushort4*)&outCMh[oc] = h4;
            }
            if (outPM) {
                const int ml = wcj * 64 + fj * 16 + lr;
#pragma unroll
                for (int r = 0; r < 4; ++r) RP[(nl + r) * 128 + ml] = f2bf(vp[r]);
            }
        }
    }

    if (outPM) {
        __syncthreads();
        // coalesced write-out: 8 x 16B per thread, 4 full 256B rows per instr
#pragma unroll
        for (int i = 0; i < 8; ++i) {
            const int flat = i * 4096 + tid * 16;          // byte offset in tile
            const int nl = flat >> 8;
            const int mlb = flat & 255;
            *(us16x8*)&outPM[((size_t)bz * HW + n0 + nl) * M + m0 + (mlb >> 1)] =
                *(const us16x8*)((const char*)RP + flat);
        }
    }
}

// Row-direction scans (dirs 0/1). Taps+lam are bf16 [B][1024][HW]; u,y f32.
__global__ __launch_bounds__(256) void scan_dir(
    const unsigned short* __restrict__ w3,
    const unsigned short* __restrict__ lam,
    const float* __restrict__ u,
    float* __restrict__ y,
    int dir, int overwrite)
{
    const int wave = threadIdx.x >> 6;
    const int lane = threadIdx.x & 63;
    const int plane = blockIdx.x * 4 + wave;
    const int b = plane >> 8;
    const int c = plane & 255;

    const size_t base_w = (size_t)b * (1024 * HW) + (size_t)c * HW;
    const size_t base_u = ((size_t)b * CDIM + c) * HW;
    const size_t tapstr = (size_t)CDIM * HW;

    float h = 0.f;
    for (int s = 0; s < 64; ++s) {
        const int p = (dir == 1) ? (63 - s) : s;
        const size_t off = (size_t)p * WD + lane;
        float w0 = bf2f(w3[base_w + off]);
        float w1 = bf2f(w3[base_w + tapstr + off]);
        float w2 = bf2f(w3[base_w + 2 * tapstr + off]);
        float dn = 1.0f / (fabsf(w0) + fabsf(w1) + fabsf(w2) + 1e-6f);
        float lm = bf2f(lam[base_w + off]);
        float uu = u[base_u + off];

        float hl = __shfl_up(h, 1);
        float hr = __shfl_down(h, 1);
        if (lane == 0)  hl = 0.f;
        if (lane == 63) hr = 0.f;

        h = (w0 * hl + w1 * h + w2 * hr) * dn + lm * uu;

        if (overwrite) y[base_u + off] = h;
        else           y[base_u + off] += h;
    }
}

// Column-direction scans (dirs 2/3), LDS-tiled. Taps/lam bf16, u/y f32.
__global__ __launch_bounds__(128) void scan_dir_t(
    const unsigned short* __restrict__ w3,
    const unsigned short* __restrict__ lam,
    const float* __restrict__ u,
    float* __restrict__ y,
    int dir)
{
    __shared__ float T[2][5][64][CH + 1];
    const int wv = threadIdx.x >> 6;
    const int lane = threadIdx.x & 63;
    const int plane = blockIdx.x * 2 + wv;
    const int b = plane >> 8;
    const int c = plane & 255;

    const size_t base_w = (size_t)b * (1024 * HW) + (size_t)c * HW;
    const size_t base_u = ((size_t)b * CDIM + c) * HW;
    const size_t tapstr = (size_t)CDIM * HW;
    const int rr = lane >> 2;
    const int q  = lane & 3;

    const unsigned short* hsrc[4];
    hsrc[0] = w3 + base_w;
    hsrc[1] = w3 + base_w + tapstr;
    hsrc[2] = w3 + base_w + 2 * tapstr;
    hsrc[3] = lam + base_w;

    float h = 0.f;
    for (int ci = 0; ci < 4; ++ci) {
        const int p0 = (dir == 3) ? (48 - ci * 16) : (ci * 16);
#pragma unroll
        for (int a = 0; a < 4; ++a) {
            const unsigned short* s = hsrc[a];
#pragma unroll
            for (int i = 0; i < 4; ++i) {
                const int r = i * 16 + rr;
                const ushort4 v = *(const ushort4*)(s + (size_t)r * WD + p0 + q * 4);
                T[wv][a][r][q * 4 + 0] = bf2f(v.x);
                T[wv][a][r][q * 4 + 1] = bf2f(v.y);
                T[wv][a][r][q * 4 + 2] = bf2f(v.z);
                T[wv][a][r][q * 4 + 3] = bf2f(v.w);
            }
        }
#pragma unroll
        for (int i = 0; i < 4; ++i) {
            const int r = i * 16 + rr;
            const float4 v = *(const float4*)(u + base_u + (size_t)r * WD + p0 + q * 4);
            T[wv][4][r][q * 4 + 0] = v.x;
            T[wv][4][r][q * 4 + 1] = v.y;
            T[wv][4][r][q * 4 + 2] = v.z;
            T[wv][4][r][q * 4 + 3] = v.w;
        }
        for (int t = 0; t < CH; ++t) {
            const int pp = (dir == 3) ? (CH - 1 - t) : t;
            float w0 = T[wv][0][lane][pp];
            float w1 = T[wv][1][lane][pp];
            float w2 = T[wv][2][lane][pp];
            float dn = 1.0f / (fabsf(w0) + fabsf(w1) + fabsf(w2) + 1e-6f);
            float lm = T[wv][3][lane][pp];
            float uu = T[wv][4][lane][pp];

            float hl = __shfl_up(h, 1);
            float hr = __shfl_down(h, 1);
            if (lane == 0)  hl = 0.f;
            if (lane == 63) hr = 0.f;

            h = (w0 * hl + w1 * h + w2 * hr) * dn + lm * uu;
            T[wv][4][lane][pp] = h;
        }
#pragma unroll
        for (int i = 0; i < 4; ++i) {
            const int r = i * 16 + rr;
            const size_t g = base_u + (size_t)r * WD + p0 + q * 4;
            float4 old = *(const float4*)(y + g);
            old.x += T[wv][4][r][q * 4 + 0];
            old.y += T[wv][4][r][q * 4 + 1];
            old.z += T[wv][4][r][q * 4 + 2];
            old.w += T[wv][4][r][q * 4 + 3];
            *(float4*)(y + g) = old;
        }
    }
}

extern "C" void kernel_launch(void* const* d_in, const int* in_sizes, int n_in,
                              void* d_out, int out_size, void* d_ws, size_t ws_size,
                              hipStream_t stream)
{
    const float* x  = (const float*)d_in[0];
    const float* Wu = (const float*)d_in[1];
    const float* bu = (const float*)d_in[2];
    const float* Ww = (const float*)d_in[3];
    const float* bw = (const float*)d_in[4];
    const float* Wl = (const float*)d_in[5];
    const float* bl = (const float*)d_in[6];
    const float* Wo = (const float*)d_in[7];
    const float* bo = (const float*)d_in[8];
    const float* W1 = (const float*)d_in[9];
    const float* b1 = (const float*)d_in[10];
    const float* W2 = (const float*)d_in[11];
    const float* b2 = (const float*)d_in[12];
    float* out = (float*)d_out;

    // ws layout (~188 MB; >=255 MB proven available):
    unsigned short* wlh = (unsigned short*)d_ws;            // [8][1024][4096] bf16 taps+lam
    float* u_  = (float*)(wlh + 33554432);                  // [8][256][4096] f32; later x2c
    float* y_  = u_ + 8388608;                              // [8][256][4096] f32
    unsigned short* xT  = (unsigned short*)(y_ + 8388608);  // [8][4096][256] bf16
    unsigned short* yT  = xT + 8388608;
    unsigned short* x2T = yT + 8388608;
    unsigned short* Wt  = x2T + 8388608;
    float* biasP = (float*)(Wt + 1703936);
    float* x2c = u_;                                        // alias (u_ dead after scans)
    unsigned short* hT = wlh;                               // [8][4096][1024] bf16, alias

    dim3 blk(256);

    pack_weights<<<dim3(6656), blk, 0, stream>>>(Wu, Ww, Wl, Wo, W1, W2,
                                                 bu, bw, bl, bo, b1, b2, Wt, biasP);
    transpose_to_bf<<<dim3(64, 4, 8), blk, 0, stream>>>(x, xT);

    // u = Wu @ x + bu  (f32 channel-major for scans)
    gemm_mfma<<<dim3(32, 2, 8), blk, 0, stream>>>(xT, Wt, biasP, 256, 256,
                                                  u_, nullptr, nullptr, nullptr, E_NONE);

    for (int dir = 0; dir < 4; ++dir) {
        // fused taps(768)+lam(256) GEMM -> bf16 channel-major; sigmoid on lam rows
        gemm_mfma<<<dim3(32, 8, 8), blk, 0, stream>>>(
            xT, Wt + 65536 + (size_t)dir * 262144, biasP + 256 + dir * 1024,
            256, 1024, nullptr, wlh, nullptr, nullptr, E_SIG768);
        if (dir < 2)
            scan_dir<<<dim3(512), blk, 0, stream>>>(wlh, wlh + 3145728, u_, y_,
                                                    dir, dir == 0 ? 1 : 0);
        else
            scan_dir_t<<<dim3(1024), dim3(128), 0, stream>>>(wlh, wlh + 3145728,
                                                             u_, y_, dir);
    }

    transpose_to_bf<<<dim3(64, 4, 8), blk, 0, stream>>>(y_, yT);

    // x2 = x + Wo @ y + bo : f32 CM (x2c) + bf16 PM (x2T)
    gemm_mfma<<<dim3(32, 2, 8), blk, 0, stream>>>(yT, Wt + 1114112, biasP + 4352,
                                                  256, 256, x2c, nullptr, x2T, x, E_RES);
    // h = gelu(x2 @ W1 + b1) : bf16 PM only
    gemm_mfma<<<dim3(32, 8, 8), blk, 0, stream>>>(x2T, Wt + 1179648, biasP + 4608,
                                                  256, 1024, nullptr, nullptr, hT, nullptr, E_GELU);
    // out = x2 + h @ W2 + b2 : f32 CM = d_out
    gemm_mfma<<<dim3(32, 2, 8), blk, 0, stream>>>(hT, Wt + 1441792, biasP + 5632,
                                                  1024, 256, out, nullptr, nullptr, x2c, E_RES);
}

// Round 10
// 495.132 us; speedup vs baseline: 8.6272x; 1.0762x over previous
//
#include <hip/hip_runtime.h>
#include <hip/hip_bf16.h>
#include <math.h>

#define HW 4096
#define WD 64
#define CDIM 256
#define BATCH 8
#define CH 16

typedef __attribute__((ext_vector_type(8))) short s16x8;
typedef __attribute__((ext_vector_type(8))) __bf16 b16x8;
typedef __attribute__((ext_vector_type(4))) float f32x4;
typedef __attribute__((ext_vector_type(8))) unsigned short us16x8;

enum { E_NONE = 0, E_SIG768 = 1, E_GELU = 2, E_RES = 3 };

__device__ __forceinline__ unsigned short f2bf(float f) {
    union { float f; unsigned u; } v; v.f = f;
    unsigned r = (v.u + 0x7fffu + ((v.u >> 16) & 1u)) >> 16;
    return (unsigned short)r;
}
__device__ __forceinline__ float bf2f(unsigned short h) {
    union { unsigned u; float f; } v; v.u = ((unsigned)h) << 16; return v.f;
}
// D.lo16 = bf16(lo), D.hi16 = bf16(hi); RNE. No builtin on gfx950 -> asm.
__device__ __forceinline__ unsigned cvt_pk_bf16(float lo, float hi) {
    unsigned r;
    asm("v_cvt_pk_bf16_f32 %0, %1, %2" : "=v"(r) : "v"(lo), "v"(hi));
    return r;
}

__device__ __forceinline__ void gload16(const void* g, void* l) {
    __builtin_amdgcn_global_load_lds(
        (const __attribute__((address_space(1))) void*)g,
        (__attribute__((address_space(3))) void*)l, 16, 0, 0);
}

__device__ __forceinline__ f32x4 mfma_bf16(s16x8 a, s16x8 b, f32x4 c) {
    return __builtin_amdgcn_mfma_f32_16x16x32_bf16(
        __builtin_bit_cast(b16x8, a), __builtin_bit_cast(b16x8, b), c, 0, 0, 0);
}

// Pack all weights to bf16 [M][K] row-major blocks + packed bias vector.
__global__ __launch_bounds__(256) void pack_weights(
    const float* __restrict__ Wu, const float* __restrict__ Ww,
    const float* __restrict__ Wl, const float* __restrict__ Wo,
    const float* __restrict__ W1, const float* __restrict__ W2,
    const float* __restrict__ bu, const float* __restrict__ bw,
    const float* __restrict__ bl, const float* __restrict__ bo,
    const float* __restrict__ b1, const float* __restrict__ b2,
    unsigned short* __restrict__ Wt, float* __restrict__ biasP)
{
    const int gid = blockIdx.x * 256 + threadIdx.x;
    if (gid < 1703936) {
        float v;
        if (gid < 65536) { v = Wu[gid]; }
        else if (gid < 1114112) {
            int t = gid - 65536; int d = t >> 18; int r = t & 262143;
            int m = r >> 8; int k = r & 255;
            v = (m < 768) ? Ww[(size_t)(d * 768 + m) * 256 + k]
                          : Wl[(size_t)(d * 256 + (m - 768)) * 256 + k];
        }
        else if (gid < 1179648) { v = Wo[gid - 1114112]; }
        else if (gid < 1441792) {
            int t = gid - 1179648; int m = t >> 8; int k = t & 255;
            v = W1[(size_t)k * 1024 + m];
        }
        else {
            int t = gid - 1441792; int m = t >> 10; int k = t & 1023;
            v = W2[(size_t)k * 256 + m];
        }
        Wt[gid] = f2bf(v);
    }
    if (gid < 5888) {
        float v;
        if (gid < 256) v = bu[gid];
        else if (gid < 4352) {
            int t = gid - 256; int d = t >> 10; int r = t & 1023;
            v = (r < 768) ? bw[d * 768 + r] : bl[d * 256 + (r - 768)];
        }
        else if (gid < 4608) v = bo[gid - 4352];
        else if (gid < 5632) v = b1[gid - 4608];
        else v = b2[gid - 5632];
        biasP[gid] = v;
    }
}

// fp32 channel-major [B][256][4096] -> bf16 pixel-major [B][4096][256]
__global__ __launch_bounds__(256) void transpose_to_bf(
    const float* __restrict__ src, unsigned short* __restrict__ dst)
{
    __shared__ float T[64][65];
    const int t = threadIdx.x;
    const int n0 = blockIdx.x * 64, c0 = blockIdx.y * 64, b = blockIdx.z;
    const int nl = t & 63, cg = t >> 6;
#pragma unroll
    for (int i = 0; i < 16; ++i) {
        int cl = cg + i * 4;
        T[cl][nl] = src[((size_t)b * 256 + c0 + cl) * HW + n0 + nl];
    }
    __syncthreads();
#pragma unroll
    for (int i = 0; i < 16; ++i) {
        int nl2 = cg + i * 4;
        dst[((size_t)b * HW + n0 + nl2) * 256 + c0 + (t & 63)] = f2bf(T[t & 63][nl2]);
    }
}

// MFMA GEMM, 128x128 tile, 4 waves 2x2, 16x16x32, BK=32.
// T4 counted-vmcnt pipeline depth 2 (validated r9: 94->64us).
// This round: epilogue VALU diet - cvt_pk bf16 pairs, __expf-based
// sigmoid/GELU, hoisted staging pointers.
__global__ __launch_bounds__(256) void gemm_mfma(
    const unsigned short* __restrict__ Abf,
    const unsigned short* __restrict__ Wbf,
    const float* __restrict__ bias,
    int K, int M,
    float* __restrict__ outCM,
    unsigned short* __restrict__ outCMh,
    unsigned short* __restrict__ outPM,
    const float* __restrict__ resCM,
    int epi)
{
    __shared__ __align__(16) char SMEM[49152];     // 3 bufs x (A 8KB + B 8KB)
    const int tid = threadIdx.x;
    const int w = tid >> 6, l = tid & 63;
    const int n0 = blockIdx.x * 128;
    const int m0 = blockIdx.y * 128;
    const int bz = blockIdx.z;
    const int wpi = w >> 1, wcj = w & 1;
    const int lr = l & 15, lg = l >> 4;

    const unsigned short* Ab = Abf + (size_t)bz * HW * K;

    f32x4 acc[4][4];
#pragma unroll
    for (int i = 0; i < 4; ++i)
#pragma unroll
        for (int j = 0; j < 4; ++j) acc[i][j] = (f32x4)0.f;

    const int sko = (((l & 3) ^ ((l >> 3) & 3)) * 8);   // swizzled k-chunk (elems)
    const int rsw = (lr >> 1) & 3;                      // read-side XOR
    const int row_l = (l >> 2);

    // hoisted staging pointers + LDS dest offsets (chunks c0 = 2w, c1 = 2w+1)
    const int c0 = w * 2, c1 = c0 + 1;
    const unsigned short* pA0 = Ab  + (size_t)(n0 + c0 * 16 + row_l) * K + sko;
    const unsigned short* pA1 = Ab  + (size_t)(n0 + c1 * 16 + row_l) * K + sko;
    const unsigned short* pB0 = Wbf + (size_t)(m0 + c0 * 16 + row_l) * K + sko;
    const unsigned short* pB1 = Wbf + (size_t)(m0 + c1 * 16 + row_l) * K + sko;
    const int dA0 = c0 * 1024, dA1 = c1 * 1024;
    const int dB0 = 8192 + c0 * 1024, dB1 = 8192 + c1 * 1024;

#define STAGE(buf, kk)                                                         \
    {                                                                          \
        gload16(pA0 + (kk), SMEM + (buf) * 16384 + dA0);                       \
        gload16(pB0 + (kk), SMEM + (buf) * 16384 + dB0);                       \
        gload16(pA1 + (kk), SMEM + (buf) * 16384 + dA1);                       \
        gload16(pB1 + (kk), SMEM + (buf) * 16384 + dB1);                       \
    }

    const int NS = K >> 5;
    STAGE(0, 0);
    if (NS > 1) STAGE(1, 32);
    int cur = 0;
    for (int t = 0; t < NS; ++t) {
        if (t + 1 < NS) asm volatile("s_waitcnt vmcnt(4)\n\ts_barrier" ::: "memory");
        else            asm volatile("s_waitcnt vmcnt(0)\n\ts_barrier" ::: "memory");
        if (t + 2 < NS) {
            int nb = cur + 2; if (nb >= 3) nb -= 3;
            STAGE(nb, (t + 2) * 32);
        }
        const short* Ac = (const short*)(SMEM + cur * 16384);
        const short* Bc = (const short*)(SMEM + cur * 16384 + 8192);
        s16x8 av[4], bv[4];
#pragma unroll
        for (int f = 0; f < 4; ++f) {
            av[f] = *(const s16x8*)&Ac[(wpi * 64 + f * 16 + lr) * 32 + (lg ^ rsw) * 8];
            bv[f] = *(const s16x8*)&Bc[(wcj * 64 + f * 16 + lr) * 32 + (lg ^ rsw) * 8];
        }
#pragma unroll
        for (int fi = 0; fi < 4; ++fi)
#pragma unroll
            for (int fj = 0; fj < 4; ++fj)
                acc[fi][fj] = mfma_bf16(av[fi], bv[fj], acc[fi][fj]);
        if (++cur == 3) cur = 0;
    }
#undef STAGE

    unsigned short* RP = (unsigned short*)SMEM;    // 128x128 bf16 PM repack
    if (outPM) __syncthreads();                    // protect SMEM reuse

#pragma unroll
    for (int fi = 0; fi < 4; ++fi) {
#pragma unroll
        for (int fj = 0; fj < 4; ++fj) {
            const int m = m0 + wcj * 64 + fj * 16 + lr;
            const int nl = wpi * 64 + fi * 16 + lg * 4;   // tile-local n base
            const float bs = bias[m];
            const size_t oc = ((size_t)bz * M + m) * HW + n0 + nl;
            float4 v4;
            float* vp = &v4.x;
#pragma unroll
            for (int r = 0; r < 4; ++r) vp[r] = acc[fi][fj][r] + bs;
            if (epi == E_SIG768) {
                if (m >= 768)
#pragma unroll
                    for (int r = 0; r < 4; ++r) vp[r] = 1.f / (1.f + __expf(-vp[r]));
            } else if (epi == E_GELU) {
                // x*sigmoid(1.702x): |err| <= 0.021 vs exact-erf GELU,
                // below bf16 resolution of the stored hidden activations
#pragma unroll
                for (int r = 0; r < 4; ++r)
                    vp[r] = vp[r] / (1.f + __expf(-1.702f * vp[r]));
            } else if (epi == E_RES) {
                const float4 rv = *(const float4*)&resCM[oc];
                v4.x += rv.x; v4.y += rv.y; v4.z += rv.z; v4.w += rv.w;
            }
            if (outCM)  *(float4*)&outCM[oc] = v4;
            if (outCMh) {
                uint2 p;
                p.x = cvt_pk_bf16(v4.x, v4.y);
                p.y = cvt_pk_bf16(v4.z, v4.w);
                *(uint2*)&outCMh[oc] = p;
            }
            if (outPM) {
                const int ml = wcj * 64 + fj * 16 + lr;
                const unsigned p01 = cvt_pk_bf16(vp[0], vp[1]);
                const unsigned p23 = cvt_pk_bf16(vp[2], vp[3]);
                RP[(nl + 0) * 128 + ml] = (unsigned short)p01;
                RP[(nl + 1) * 128 + ml] = (unsigned short)(p01 >> 16);
                RP[(nl + 2) * 128 + ml] = (unsigned short)p23;
                RP[(nl + 3) * 128 + ml] = (unsigned short)(p23 >> 16);
            }
        }
    }

    if (outPM) {
        __syncthreads();
        // coalesced write-out: 8 x 16B per thread, 4 full 256B rows per instr
#pragma unroll
        for (int i = 0; i < 8; ++i) {
            const int flat = i * 4096 + tid * 16;          // byte offset in tile
            const int nl = flat >> 8;
            const int mlb = flat & 255;
            *(us16x8*)&outPM[((size_t)bz * HW + n0 + nl) * M + m0 + (mlb >> 1)] =
                *(const us16x8*)((const char*)RP + flat);
        }
    }
}

// Row-direction scans (dirs 0/1). Taps+lam are bf16 [B][1024][HW]; u,y f32.
__global__ __launch_bounds__(256) void scan_dir(
    const unsigned short* __restrict__ w3,
    const unsigned short* __restrict__ lam,
    const float* __restrict__ u,
    float* __restrict__ y,
    int dir, int overwrite)
{
    const int wave = threadIdx.x >> 6;
    const int lane = threadIdx.x & 63;
    const int plane = blockIdx.x * 4 + wave;
    const int b = plane >> 8;
    const int c = plane & 255;

    const size_t base_w = (size_t)b * (1024 * HW) + (size_t)c * HW;
    const size_t base_u = ((size_t)b * CDIM + c) * HW;
    const size_t tapstr = (size_t)CDIM * HW;

    float h = 0.f;
    for (int s = 0; s < 64; ++s) {
        const int p = (dir == 1) ? (63 - s) : s;
        const size_t off = (size_t)p * WD + lane;
        float w0 = bf2f(w3[base_w + off]);
        float w1 = bf2f(w3[base_w + tapstr + off]);
        float w2 = bf2f(w3[base_w + 2 * tapstr + off]);
        float dn = 1.0f / (fabsf(w0) + fabsf(w1) + fabsf(w2) + 1e-6f);
        float lm = bf2f(lam[base_w + off]);
        float uu = u[base_u + off];

        float hl = __shfl_up(h, 1);
        float hr = __shfl_down(h, 1);
        if (lane == 0)  hl = 0.f;
        if (lane == 63) hr = 0.f;

        h = (w0 * hl + w1 * h + w2 * hr) * dn + lm * uu;

        if (overwrite) y[base_u + off] = h;
        else           y[base_u + off] += h;
    }
}

// Column-direction scans (dirs 2/3), LDS-tiled. Taps/lam bf16, u/y f32.
__global__ __launch_bounds__(128) void scan_dir_t(
    const unsigned short* __restrict__ w3,
    const unsigned short* __restrict__ lam,
    const float* __restrict__ u,
    float* __restrict__ y,
    int dir)
{
    __shared__ float T[2][5][64][CH + 1];
    const int wv = threadIdx.x >> 6;
    const int lane = threadIdx.x & 63;
    const int plane = blockIdx.x * 2 + wv;
    const int b = plane >> 8;
    const int c = plane & 255;

    const size_t base_w = (size_t)b * (1024 * HW) + (size_t)c * HW;
    const size_t base_u = ((size_t)b * CDIM + c) * HW;
    const size_t tapstr = (size_t)CDIM * HW;
    const int rr = lane >> 2;
    const int q  = lane & 3;

    const unsigned short* hsrc[4];
    hsrc[0] = w3 + base_w;
    hsrc[1] = w3 + base_w + tapstr;
    hsrc[2] = w3 + base_w + 2 * tapstr;
    hsrc[3] = lam + base_w;

    float h = 0.f;
    for (int ci = 0; ci < 4; ++ci) {
        const int p0 = (dir == 3) ? (48 - ci * 16) : (ci * 16);
#pragma unroll
        for (int a = 0; a < 4; ++a) {
            const unsigned short* s = hsrc[a];
#pragma unroll
            for (int i = 0; i < 4; ++i) {
                const int r = i * 16 + rr;
                const ushort4 v = *(const ushort4*)(s + (size_t)r * WD + p0 + q * 4);
                T[wv][a][r][q * 4 + 0] = bf2f(v.x);
                T[wv][a][r][q * 4 + 1] = bf2f(v.y);
                T[wv][a][r][q * 4 + 2] = bf2f(v.z);
                T[wv][a][r][q * 4 + 3] = bf2f(v.w);
            }
        }
#pragma unroll
        for (int i = 0; i < 4; ++i) {
            const int r = i * 16 + rr;
            const float4 v = *(const float4*)(u + base_u + (size_t)r * WD + p0 + q * 4);
            T[wv][4][r][q * 4 + 0] = v.x;
            T[wv][4][r][q * 4 + 1] = v.y;
            T[wv][4][r][q * 4 + 2] = v.z;
            T[wv][4][r][q * 4 + 3] = v.w;
        }
        for (int t = 0; t < CH; ++t) {
            const int pp = (dir == 3) ? (CH - 1 - t) : t;
            float w0 = T[wv][0][lane][pp];
            float w1 = T[wv][1][lane][pp];
            float w2 = T[wv][2][lane][pp];
            float dn = 1.0f / (fabsf(w0) + fabsf(w1) + fabsf(w2) + 1e-6f);
            float lm = T[wv][3][lane][pp];
            float uu = T[wv][4][lane][pp];

            float hl = __shfl_up(h, 1);
            float hr = __shfl_down(h, 1);
            if (lane == 0)  hl = 0.f;
            if (lane == 63) hr = 0.f;

            h = (w0 * hl + w1 * h + w2 * hr) * dn + lm * uu;
            T[wv][4][lane][pp] = h;
        }
#pragma unroll
        for (int i = 0; i < 4; ++i) {
            const int r = i * 16 + rr;
            const size_t g = base_u + (size_t)r * WD + p0 + q * 4;
            float4 old = *(const float4*)(y + g);
            old.x += T[wv][4][r][q * 4 + 0];
            old.y += T[wv][4][r][q * 4 + 1];
            old.z += T[wv][4][r][q * 4 + 2];
            old.w += T[wv][4][r][q * 4 + 3];
            *(float4*)(y + g) = old;
        }
    }
}

extern "C" void kernel_launch(void* const* d_in, const int* in_sizes, int n_in,
                              void* d_out, int out_size, void* d_ws, size_t ws_size,
                              hipStream_t stream)
{
    const float* x  = (const float*)d_in[0];
    const float* Wu = (const float*)d_in[1];
    const float* bu = (const float*)d_in[2];
    const float* Ww = (const float*)d_in[3];
    const float* bw = (const float*)d_in[4];
    const float* Wl = (const float*)d_in[5];
    const float* bl = (const float*)d_in[6];
    const float* Wo = (const float*)d_in[7];
    const float* bo = (const float*)d_in[8];
    const float* W1 = (const float*)d_in[9];
    const float* b1 = (const float*)d_in[10];
    const float* W2 = (const float*)d_in[11];
    const float* b2 = (const float*)d_in[12];
    float* out = (float*)d_out;

    // ws layout (~188 MB; >=255 MB proven available):
    unsigned short* wlh = (unsigned short*)d_ws;            // [8][1024][4096] bf16 taps+lam
    float* u_  = (float*)(wlh + 33554432);                  // [8][256][4096] f32; later x2c
    float* y_  = u_ + 8388608;                              // [8][256][4096] f32
    unsigned short* xT  = (unsigned short*)(y_ + 8388608);  // [8][4096][256] bf16
    unsigned short* yT  = xT + 8388608;
    unsigned short* x2T = yT + 8388608;
    unsigned short* Wt  = x2T + 8388608;
    float* biasP = (float*)(Wt + 1703936);
    float* x2c = u_;                                        // alias (u_ dead after scans)
    unsigned short* hT = wlh;                               // [8][4096][1024] bf16, alias

    dim3 blk(256);

    pack_weights<<<dim3(6656), blk, 0, stream>>>(Wu, Ww, Wl, Wo, W1, W2,
                                                 bu, bw, bl, bo, b1, b2, Wt, biasP);
    transpose_to_bf<<<dim3(64, 4, 8), blk, 0, stream>>>(x, xT);

    // u = Wu @ x + bu  (f32 channel-major for scans)
    gemm_mfma<<<dim3(32, 2, 8), blk, 0, stream>>>(xT, Wt, biasP, 256, 256,
                                                  u_, nullptr, nullptr, nullptr, E_NONE);

    for (int dir = 0; dir < 4; ++dir) {
        // fused taps(768)+lam(256) GEMM -> bf16 channel-major; sigmoid on lam rows
        gemm_mfma<<<dim3(32, 8, 8), blk, 0, stream>>>(
            xT, Wt + 65536 + (size_t)dir * 262144, biasP + 256 + dir * 1024,
            256, 1024, nullptr, wlh, nullptr, nullptr, E_SIG768);
        if (dir < 2)
            scan_dir<<<dim3(512), blk, 0, stream>>>(wlh, wlh + 3145728, u_, y_,
                                                    dir, dir == 0 ? 1 : 0);
        else
            scan_dir_t<<<dim3(1024), dim3(128), 0, stream>>>(wlh, wlh + 3145728,
                                                             u_, y_, dir);
    }

    transpose_to_bf<<<dim3(64, 4, 8), blk, 0, stream>>>(y_, yT);

    // x2 = x + Wo @ y + bo : f32 CM (x2c) + bf16 PM (x2T)
    gemm_mfma<<<dim3(32, 2, 8), blk, 0, stream>>>(yT, Wt + 1114112, biasP + 4352,
                                                  256, 256, x2c, nullptr, x2T, x, E_RES);
    // h = gelu(x2 @ W1 + b1) : bf16 PM only
    gemm_mfma<<<dim3(32, 8, 8), blk, 0, stream>>>(x2T, Wt + 1179648, biasP + 4608,
                                                  256, 1024, nullptr, nullptr, hT, nullptr, E_GELU);
    // out = x2 + h @ W2 + b2 : f32 CM = d_out
    gemm_mfma<<<dim3(32, 2, 8), blk, 0, stream>>>(hT, Wt + 1441792, biasP + 5632,
                                                  1024, 256, out, nullptr, nullptr, x2c, E_RES);
}

// Round 11
// 446.562 us; speedup vs baseline: 9.5655x; 1.1088x over previous
//
#include <hip/hip_runtime.h>
#include <hip/hip_bf16.h>
#include <math.h>

#define HW 4096
#define WD 64
#define CDIM 256
#define BATCH 8
#define CHT 32

typedef __attribute__((ext_vector_type(8))) short s16x8;
typedef __attribute__((ext_vector_type(8))) __bf16 b16x8;
typedef __attribute__((ext_vector_type(4))) float f32x4;
typedef __attribute__((ext_vector_type(8))) unsigned short us16x8;

enum { E_NONE = 0, E_SIG768 = 1, E_GELU = 2, E_RES = 3 };

__device__ __forceinline__ unsigned short f2bf(float f) {
    union { float f; unsigned u; } v; v.f = f;
    unsigned r = (v.u + 0x7fffu + ((v.u >> 16) & 1u)) >> 16;
    return (unsigned short)r;
}
__device__ __forceinline__ float bf2f(unsigned short h) {
    union { unsigned u; float f; } v; v.u = ((unsigned)h) << 16; return v.f;
}
// D.lo16 = bf16(lo), D.hi16 = bf16(hi); RNE. No builtin on gfx950 -> asm.
__device__ __forceinline__ unsigned cvt_pk_bf16(float lo, float hi) {
    unsigned r;
    asm("v_cvt_pk_bf16_f32 %0, %1, %2" : "=v"(r) : "v"(lo), "v"(hi));
    return r;
}

__device__ __forceinline__ void gload16(const void* g, void* l) {
    __builtin_amdgcn_global_load_lds(
        (const __attribute__((address_space(1))) void*)g,
        (__attribute__((address_space(3))) void*)l, 16, 0, 0);
}

__device__ __forceinline__ f32x4 mfma_bf16(s16x8 a, s16x8 b, f32x4 c) {
    return __builtin_amdgcn_mfma_f32_16x16x32_bf16(
        __builtin_bit_cast(b16x8, a), __builtin_bit_cast(b16x8, b), c, 0, 0, 0);
}

// Pack all weights to bf16 [M][K] row-major blocks + packed bias vector.
__global__ __launch_bounds__(256) void pack_weights(
    const float* __restrict__ Wu, const float* __restrict__ Ww,
    const float* __restrict__ Wl, const float* __restrict__ Wo,
    const float* __restrict__ W1, const float* __restrict__ W2,
    const float* __restrict__ bu, const float* __restrict__ bw,
    const float* __restrict__ bl, const float* __restrict__ bo,
    const float* __restrict__ b1, const float* __restrict__ b2,
    unsigned short* __restrict__ Wt, float* __restrict__ biasP)
{
    const int gid = blockIdx.x * 256 + threadIdx.x;
    if (gid < 1703936) {
        float v;
        if (gid < 65536) { v = Wu[gid]; }
        else if (gid < 1114112) {
            int t = gid - 65536; int d = t >> 18; int r = t & 262143;
            int m = r >> 8; int k = r & 255;
            v = (m < 768) ? Ww[(size_t)(d * 768 + m) * 256 + k]
                          : Wl[(size_t)(d * 256 + (m - 768)) * 256 + k];
        }
        else if (gid < 1179648) { v = Wo[gid - 1114112]; }
        else if (gid < 1441792) {
            int t = gid - 1179648; int m = t >> 8; int k = t & 255;
            v = W1[(size_t)k * 1024 + m];
        }
        else {
            int t = gid - 1441792; int m = t >> 10; int k = t & 1023;
            v = W2[(size_t)k * 256 + m];
        }
        Wt[gid] = f2bf(v);
    }
    if (gid < 5888) {
        float v;
        if (gid < 256) v = bu[gid];
        else if (gid < 4352) {
            int t = gid - 256; int d = t >> 10; int r = t & 1023;
            v = (r < 768) ? bw[d * 768 + r] : bl[d * 256 + (r - 768)];
        }
        else if (gid < 4608) v = bo[gid - 4352];
        else if (gid < 5632) v = b1[gid - 4608];
        else v = b2[gid - 5632];
        biasP[gid] = v;
    }
}

// fp32 channel-major [B][256][4096] -> bf16 pixel-major [B][4096][256]
__global__ __launch_bounds__(256) void transpose_to_bf(
    const float* __restrict__ src, unsigned short* __restrict__ dst)
{
    __shared__ float T[64][65];
    const int t = threadIdx.x;
    const int n0 = blockIdx.x * 64, c0 = blockIdx.y * 64, b = blockIdx.z;
    const int nl = t & 63, cg = t >> 6;
#pragma unroll
    for (int i = 0; i < 16; ++i) {
        int cl = cg + i * 4;
        T[cl][nl] = src[((size_t)b * 256 + c0 + cl) * HW + n0 + nl];
    }
    __syncthreads();
#pragma unroll
    for (int i = 0; i < 16; ++i) {
        int nl2 = cg + i * 4;
        dst[((size_t)b * HW + n0 + nl2) * 256 + c0 + (t & 63)] = f2bf(T[t & 63][nl2]);
    }
}

// MFMA GEMM, 128x128 tile, 4 waves 2x2, 16x16x32, BK=32.
// T4 counted-vmcnt pipeline depth 2 (validated r9) + epilogue diet (r10).
__global__ __launch_bounds__(256) void gemm_mfma(
    const unsigned short* __restrict__ Abf,
    const unsigned short* __restrict__ Wbf,
    const float* __restrict__ bias,
    int K, int M,
    float* __restrict__ outCM,
    unsigned short* __restrict__ outCMh,
    unsigned short* __restrict__ outPM,
    const float* __restrict__ resCM,
    int epi)
{
    __shared__ __align__(16) char SMEM[49152];     // 3 bufs x (A 8KB + B 8KB)
    const int tid = threadIdx.x;
    const int w = tid >> 6, l = tid & 63;
    const int n0 = blockIdx.x * 128;
    const int m0 = blockIdx.y * 128;
    const int bz = blockIdx.z;
    const int wpi = w >> 1, wcj = w & 1;
    const int lr = l & 15, lg = l >> 4;

    const unsigned short* Ab = Abf + (size_t)bz * HW * K;

    f32x4 acc[4][4];
#pragma unroll
    for (int i = 0; i < 4; ++i)
#pragma unroll
        for (int j = 0; j < 4; ++j) acc[i][j] = (f32x4)0.f;

    const int sko = (((l & 3) ^ ((l >> 3) & 3)) * 8);   // swizzled k-chunk (elems)
    const int rsw = (lr >> 1) & 3;                      // read-side XOR
    const int row_l = (l >> 2);

    // hoisted staging pointers + LDS dest offsets (chunks c0 = 2w, c1 = 2w+1)
    const int c0 = w * 2, c1 = c0 + 1;
    const unsigned short* pA0 = Ab  + (size_t)(n0 + c0 * 16 + row_l) * K + sko;
    const unsigned short* pA1 = Ab  + (size_t)(n0 + c1 * 16 + row_l) * K + sko;
    const unsigned short* pB0 = Wbf + (size_t)(m0 + c0 * 16 + row_l) * K + sko;
    const unsigned short* pB1 = Wbf + (size_t)(m0 + c1 * 16 + row_l) * K + sko;
    const int dA0 = c0 * 1024, dA1 = c1 * 1024;
    const int dB0 = 8192 + c0 * 1024, dB1 = 8192 + c1 * 1024;

#define STAGE(buf, kk)                                                         \
    {                                                                          \
        gload16(pA0 + (kk), SMEM + (buf) * 16384 + dA0);                       \
        gload16(pB0 + (kk), SMEM + (buf) * 16384 + dB0);                       \
        gload16(pA1 + (kk), SMEM + (buf) * 16384 + dA1);                       \
        gload16(pB1 + (kk), SMEM + (buf) * 16384 + dB1);                       \
    }

    const int NS = K >> 5;
    STAGE(0, 0);
    if (NS > 1) STAGE(1, 32);
    int cur = 0;
    for (int t = 0; t < NS; ++t) {
        if (t + 1 < NS) asm volatile("s_waitcnt vmcnt(4)\n\ts_barrier" ::: "memory");
        else            asm volatile("s_waitcnt vmcnt(0)\n\ts_barrier" ::: "memory");
        if (t + 2 < NS) {
            int nb = cur + 2; if (nb >= 3) nb -= 3;
            STAGE(nb, (t + 2) * 32);
        }
        const short* Ac = (const short*)(SMEM + cur * 16384);
        const short* Bc = (const short*)(SMEM + cur * 16384 + 8192);
        s16x8 av[4], bv[4];
#pragma unroll
        for (int f = 0; f < 4; ++f) {
            av[f] = *(const s16x8*)&Ac[(wpi * 64 + f * 16 + lr) * 32 + (lg ^ rsw) * 8];
            bv[f] = *(const s16x8*)&Bc[(wcj * 64 + f * 16 + lr) * 32 + (lg ^ rsw) * 8];
        }
#pragma unroll
        for (int fi = 0; fi < 4; ++fi)
#pragma unroll
            for (int fj = 0; fj < 4; ++fj)
                acc[fi][fj] = mfma_bf16(av[fi], bv[fj], acc[fi][fj]);
        if (++cur == 3) cur = 0;
    }
#undef STAGE

    unsigned short* RP = (unsigned short*)SMEM;    // 128x128 bf16 PM repack
    if (outPM) __syncthreads();                    // protect SMEM reuse

#pragma unroll
    for (int fi = 0; fi < 4; ++fi) {
#pragma unroll
        for (int fj = 0; fj < 4; ++fj) {
            const int m = m0 + wcj * 64 + fj * 16 + lr;
            const int nl = wpi * 64 + fi * 16 + lg * 4;   // tile-local n base
            const float bs = bias[m];
            const size_t oc = ((size_t)bz * M + m) * HW + n0 + nl;
            float4 v4;
            float* vp = &v4.x;
#pragma unroll
            for (int r = 0; r < 4; ++r) vp[r] = acc[fi][fj][r] + bs;
            if (epi == E_SIG768) {
                if (m >= 768)
#pragma unroll
                    for (int r = 0; r < 4; ++r) vp[r] = 1.f / (1.f + __expf(-vp[r]));
            } else if (epi == E_GELU) {
                // x*sigmoid(1.702x): |err| <= 0.021 vs exact-erf GELU
#pragma unroll
                for (int r = 0; r < 4; ++r)
                    vp[r] = vp[r] / (1.f + __expf(-1.702f * vp[r]));
            } else if (epi == E_RES) {
                const float4 rv = *(const float4*)&resCM[oc];
                v4.x += rv.x; v4.y += rv.y; v4.z += rv.z; v4.w += rv.w;
            }
            if (outCM)  *(float4*)&outCM[oc] = v4;
            if (outCMh) {
                uint2 p;
                p.x = cvt_pk_bf16(v4.x, v4.y);
                p.y = cvt_pk_bf16(v4.z, v4.w);
                *(uint2*)&outCMh[oc] = p;
            }
            if (outPM) {
                const int ml = wcj * 64 + fj * 16 + lr;
                const unsigned p01 = cvt_pk_bf16(vp[0], vp[1]);
                const unsigned p23 = cvt_pk_bf16(vp[2], vp[3]);
                RP[(nl + 0) * 128 + ml] = (unsigned short)p01;
                RP[(nl + 1) * 128 + ml] = (unsigned short)(p01 >> 16);
                RP[(nl + 2) * 128 + ml] = (unsigned short)p23;
                RP[(nl + 3) * 128 + ml] = (unsigned short)(p23 >> 16);
            }
        }
    }

    if (outPM) {
        __syncthreads();
#pragma unroll
        for (int i = 0; i < 8; ++i) {
            const int flat = i * 4096 + tid * 16;          // byte offset in tile
            const int nl = flat >> 8;
            const int mlb = flat & 255;
            *(us16x8*)&outPM[((size_t)bz * HW + n0 + nl) * M + m0 + (mlb >> 1)] =
                *(const us16x8*)((const char*)RP + flat);
        }
    }
}

// Row-direction scans (dirs 0/1), register-prefetched (s+1 loads issue
// before step-s compute; hides one step of load latency).
__global__ __launch_bounds__(256) void scan_dir(
    const unsigned short* __restrict__ w3,
    const unsigned short* __restrict__ lam,
    const float* __restrict__ u,
    float* __restrict__ y,
    int dir, int overwrite)
{
    const int wave = threadIdx.x >> 6;
    const int lane = threadIdx.x & 63;
    const int plane = blockIdx.x * 4 + wave;
    const int b = plane >> 8;
    const int c = plane & 255;

    const size_t base_w = (size_t)b * (1024 * HW) + (size_t)c * HW;
    const size_t base_u = ((size_t)b * CDIM + c) * HW;
    const size_t tapstr = (size_t)CDIM * HW;

    int p = (dir == 1) ? 63 : 0;
    size_t off = (size_t)p * WD + lane;
    float w0 = bf2f(w3[base_w + off]);
    float w1 = bf2f(w3[base_w + tapstr + off]);
    float w2 = bf2f(w3[base_w + 2 * tapstr + off]);
    float lm = bf2f(lam[base_w + off]);
    float uu = u[base_u + off];
    float yv = overwrite ? 0.f : y[base_u + off];

    float h = 0.f;
    for (int s = 0; s < 64; ++s) {
        float nw0 = 0.f, nw1 = 0.f, nw2 = 0.f, nlm = 0.f, nuu = 0.f, nyv = 0.f;
        size_t noff = 0;
        if (s + 1 < 64) {
            const int pn = (dir == 1) ? (62 - s) : (s + 1);
            noff = (size_t)pn * WD + lane;
            nw0 = bf2f(w3[base_w + noff]);
            nw1 = bf2f(w3[base_w + tapstr + noff]);
            nw2 = bf2f(w3[base_w + 2 * tapstr + noff]);
            nlm = bf2f(lam[base_w + noff]);
            nuu = u[base_u + noff];
            if (!overwrite) nyv = y[base_u + noff];
        }
        float dn = 1.0f / (fabsf(w0) + fabsf(w1) + fabsf(w2) + 1e-6f);
        float hl = __shfl_up(h, 1);
        float hr = __shfl_down(h, 1);
        if (lane == 0)  hl = 0.f;
        if (lane == 63) hr = 0.f;
        h = (w0 * hl + w1 * h + w2 * hr) * dn + lm * uu;
        y[base_u + off] = yv + h;
        off = noff;
        w0 = nw0; w1 = nw1; w2 = nw2; lm = nlm; uu = nuu; yv = nyv;
    }
}

// Column-direction scans (dirs 2/3), v3: CH=32 chunks (full-line tap reads),
// column-major LDS: TH[a][col][row] ushort (pad 66), U[col][row] f32 (pad 65)
// -> scan-step reads are stride-1 conflict-free; staging scatters are scalar
// LDS writes (VALU idle). 50.4 KB/block, 2 waves.
__global__ __launch_bounds__(128) void scan_dir_t(
    const unsigned short* __restrict__ w3,
    const unsigned short* __restrict__ lam,
    const float* __restrict__ u,
    float* __restrict__ y,
    int dir)
{
    __shared__ unsigned short TH[2][4][CHT][66];   // 33.0 KB
    __shared__ float U[2][CHT][65];                // 16.25 KB
    const int wv = threadIdx.x >> 6;
    const int lane = threadIdx.x & 63;
    const int plane = blockIdx.x * 2 + wv;
    const int b = plane >> 8;
    const int c = plane & 255;

    const size_t base_w = (size_t)b * (1024 * HW) + (size_t)c * HW;
    const size_t base_u = ((size_t)b * CDIM + c) * HW;
    const size_t tapstr = (size_t)CDIM * HW;
    const int rr4 = lane >> 2, q4 = lane & 3;      // taps: 4 lanes/row, 16B each
    const int rr8 = lane >> 3, q8 = lane & 7;      // u/y: 8 lanes/row, 16B each

    float h = 0.f;
    for (int ci = 0; ci < 2; ++ci) {
        const int p0 = (dir == 3) ? (CHT - ci * CHT) : (ci * CHT);

        // stage taps+lam: full 64B-line reads, transpose-scatter into LDS
#pragma unroll
        for (int a = 0; a < 4; ++a) {
            const unsigned short* s = (a < 3) ? (w3 + base_w + a * tapstr)
                                              : (lam + base_w);
#pragma unroll
            for (int i = 0; i < 4; ++i) {
                const int r = i * 16 + rr4;
                const us16x8 v = *(const us16x8*)(s + (size_t)r * WD + p0 + q4 * 8);
#pragma unroll
                for (int j = 0; j < 8; ++j) TH[wv][a][q4 * 8 + j][r] = v[j];
            }
        }
        // stage u (f32, full-line float4 reads)
#pragma unroll
        for (int i = 0; i < 8; ++i) {
            const int r = i * 8 + rr8;
            const float4 v = *(const float4*)(u + base_u + (size_t)r * WD + p0 + q8 * 4);
            U[wv][q8 * 4 + 0][r] = v.x;
            U[wv][q8 * 4 + 1][r] = v.y;
            U[wv][q8 * 4 + 2][r] = v.z;
            U[wv][q8 * 4 + 3][r] = v.w;
        }
        // same-wave LDS ops are in-order; no cross-wave sharing -> no barrier

        for (int t = 0; t < CHT; ++t) {
            const int pp = (dir == 3) ? (CHT - 1 - t) : t;
            float w0 = bf2f(TH[wv][0][pp][lane]);
            float w1 = bf2f(TH[wv][1][pp][lane]);
            float w2 = bf2f(TH[wv][2][pp][lane]);
            float dn = 1.0f / (fabsf(w0) + fabsf(w1) + fabsf(w2) + 1e-6f);
            float lm = bf2f(TH[wv][3][pp][lane]);
            float uu = U[wv][pp][lane];

            float hl = __shfl_up(h, 1);
            float hr = __shfl_down(h, 1);
            if (lane == 0)  hl = 0.f;
            if (lane == 63) hr = 0.f;

            h = (w0 * hl + w1 * h + w2 * hr) * dn + lm * uu;
            U[wv][pp][lane] = h;                   // overwrite consumed u slot
        }

        // coalesced float4 RMW of y
#pragma unroll
        for (int i = 0; i < 8; ++i) {
            const int r = i * 8 + rr8;
            const size_t g = base_u + (size_t)r * WD + p0 + q8 * 4;
            float4 old = *(const float4*)(y + g);
            old.x += U[wv][q8 * 4 + 0][r];
            old.y += U[wv][q8 * 4 + 1][r];
            old.z += U[wv][q8 * 4 + 2][r];
            old.w += U[wv][q8 * 4 + 3][r];
            *(float4*)(y + g) = old;
        }
    }
}

extern "C" void kernel_launch(void* const* d_in, const int* in_sizes, int n_in,
                              void* d_out, int out_size, void* d_ws, size_t ws_size,
                              hipStream_t stream)
{
    const float* x  = (const float*)d_in[0];
    const float* Wu = (const float*)d_in[1];
    const float* bu = (const float*)d_in[2];
    const float* Ww = (const float*)d_in[3];
    const float* bw = (const float*)d_in[4];
    const float* Wl = (const float*)d_in[5];
    const float* bl = (const float*)d_in[6];
    const float* Wo = (const float*)d_in[7];
    const float* bo = (const float*)d_in[8];
    const float* W1 = (const float*)d_in[9];
    const float* b1 = (const float*)d_in[10];
    const float* W2 = (const float*)d_in[11];
    const float* b2 = (const float*)d_in[12];
    float* out = (float*)d_out;

    // ws layout (~188 MB; >=255 MB proven available):
    unsigned short* wlh = (unsigned short*)d_ws;            // [8][1024][4096] bf16 taps+lam
    float* u_  = (float*)(wlh + 33554432);                  // [8][256][4096] f32; later x2c
    float* y_  = u_ + 8388608;                              // [8][256][4096] f32
    unsigned short* xT  = (unsigned short*)(y_ + 8388608);  // [8][4096][256] bf16
    unsigned short* yT  = xT + 8388608;
    unsigned short* x2T = yT + 8388608;
    unsigned short* Wt  = x2T + 8388608;
    float* biasP = (float*)(Wt + 1703936);
    float* x2c = u_;                                        // alias (u_ dead after scans)
    unsigned short* hT = wlh;                               // [8][4096][1024] bf16, alias

    dim3 blk(256);

    pack_weights<<<dim3(6656), blk, 0, stream>>>(Wu, Ww, Wl, Wo, W1, W2,
                                                 bu, bw, bl, bo, b1, b2, Wt, biasP);
    transpose_to_bf<<<dim3(64, 4, 8), blk, 0, stream>>>(x, xT);

    // u = Wu @ x + bu  (f32 channel-major for scans)
    gemm_mfma<<<dim3(32, 2, 8), blk, 0, stream>>>(xT, Wt, biasP, 256, 256,
                                                  u_, nullptr, nullptr, nullptr, E_NONE);

    for (int dir = 0; dir < 4; ++dir) {
        // fused taps(768)+lam(256) GEMM -> bf16 channel-major; sigmoid on lam rows
        gemm_mfma<<<dim3(32, 8, 8), blk, 0, stream>>>(
            xT, Wt + 65536 + (size_t)dir * 262144, biasP + 256 + dir * 1024,
            256, 1024, nullptr, wlh, nullptr, nullptr, E_SIG768);
        if (dir < 2)
            scan_dir<<<dim3(512), blk, 0, stream>>>(wlh, wlh + 3145728, u_, y_,
                                                    dir, dir == 0 ? 1 : 0);
        else
            scan_dir_t<<<dim3(1024), dim3(128), 0, stream>>>(wlh, wlh + 3145728,
                                                             u_, y_, dir);
    }

    transpose_to_bf<<<dim3(64, 4, 8), blk, 0, stream>>>(y_, yT);

    // x2 = x + Wo @ y + bo : f32 CM (x2c) + bf16 PM (x2T)
    gemm_mfma<<<dim3(32, 2, 8), blk, 0, stream>>>(yT, Wt + 1114112, biasP + 4352,
                                                  256, 256, x2c, nullptr, x2T, x, E_RES);
    // h = gelu(x2 @ W1 + b1) : bf16 PM only
    gemm_mfma<<<dim3(32, 8, 8), blk, 0, stream>>>(x2T, Wt + 1179648, biasP + 4608,
                                                  256, 1024, nullptr, nullptr, hT, nullptr, E_GELU);
    // out = x2 + h @ W2 + b2 : f32 CM = d_out
    gemm_mfma<<<dim3(32, 2, 8), blk, 0, stream>>>(hT, Wt + 1441792, biasP + 5632,
                                                  1024, 256, out, nullptr, nullptr, x2c, E_RES);
}

// Round 12
// 424.925 us; speedup vs baseline: 10.0526x; 1.0509x over previous
//
#include <hip/hip_runtime.h>
#include <hip/hip_bf16.h>
#include <math.h>

#define HW 4096
#define WD 64
#define CDIM 256
#define BATCH 8
#define CHT 32

typedef __attribute__((ext_vector_type(8))) short s16x8;
typedef __attribute__((ext_vector_type(8))) __bf16 b16x8;
typedef __attribute__((ext_vector_type(4))) float f32x4;
typedef __attribute__((ext_vector_type(8))) unsigned short us16x8;

enum { E_NONE = 0, E_GELU = 2, E_RES = 3, E_RESPM = 4 };

__device__ __forceinline__ unsigned short f2bf(float f) {
    union { float f; unsigned u; } v; v.f = f;
    unsigned r = (v.u + 0x7fffu + ((v.u >> 16) & 1u)) >> 16;
    return (unsigned short)r;
}
__device__ __forceinline__ float bf2f(unsigned short h) {
    union { unsigned u; float f; } v; v.u = ((unsigned)h) << 16; return v.f;
}
// D.lo16 = bf16(lo), D.hi16 = bf16(hi); RNE. No builtin on gfx950 -> asm.
__device__ __forceinline__ unsigned cvt_pk_bf16(float lo, float hi) {
    unsigned r;
    asm("v_cvt_pk_bf16_f32 %0, %1, %2" : "=v"(r) : "v"(lo), "v"(hi));
    return r;
}

__device__ __forceinline__ void gload16(const void* g, void* l) {
    __builtin_amdgcn_global_load_lds(
        (const __attribute__((address_space(1))) void*)g,
        (__attribute__((address_space(3))) void*)l, 16, 0, 0);
}

__device__ __forceinline__ f32x4 mfma_bf16(s16x8 a, s16x8 b, f32x4 c) {
    return __builtin_amdgcn_mfma_f32_16x16x32_bf16(
        __builtin_bit_cast(b16x8, a), __builtin_bit_cast(b16x8, b), c, 0, 0, 0);
}

// Pack all weights to bf16 [M][K] row-major blocks + packed bias vector.
__global__ __launch_bounds__(256) void pack_weights(
    const float* __restrict__ Wu, const float* __restrict__ Ww,
    const float* __restrict__ Wl, const float* __restrict__ Wo,
    const float* __restrict__ W1, const float* __restrict__ W2,
    const float* __restrict__ bu, const float* __restrict__ bw,
    const float* __restrict__ bl, const float* __restrict__ bo,
    const float* __restrict__ b1, const float* __restrict__ b2,
    unsigned short* __restrict__ Wt, float* __restrict__ biasP)
{
    const int gid = blockIdx.x * 256 + threadIdx.x;
    if (gid < 1703936) {
        float v;
        if (gid < 65536) { v = Wu[gid]; }
        else if (gid < 1114112) {
            int t = gid - 65536; int d = t >> 18; int r = t & 262143;
            int m = r >> 8; int k = r & 255;
            v = (m < 768) ? Ww[(size_t)(d * 768 + m) * 256 + k]
                          : Wl[(size_t)(d * 256 + (m - 768)) * 256 + k];
        }
        else if (gid < 1179648) { v = Wo[gid - 1114112]; }
        else if (gid < 1441792) {
            int t = gid - 1179648; int m = t >> 8; int k = t & 255;
            v = W1[(size_t)k * 1024 + m];
        }
        else {
            int t = gid - 1441792; int m = t >> 10; int k = t & 1023;
            v = W2[(size_t)k * 256 + m];
        }
        Wt[gid] = f2bf(v);
    }
    if (gid < 5888) {
        float v;
        if (gid < 256) v = bu[gid];
        else if (gid < 4352) {
            int t = gid - 256; int d = t >> 10; int r = t & 1023;
            v = (r < 768) ? bw[d * 768 + r] : bl[d * 256 + (r - 768)];
        }
        else if (gid < 4608) v = bo[gid - 4352];
        else if (gid < 5632) v = b1[gid - 4608];
        else v = b2[gid - 5632];
        biasP[gid] = v;
    }
}

// fp32 channel-major [B][256][4096] -> bf16 pixel-major [B][4096][256]
__global__ __launch_bounds__(256) void transpose_to_bf(
    const float* __restrict__ src, unsigned short* __restrict__ dst)
{
    __shared__ float T[64][65];
    const int t = threadIdx.x;
    const int n0 = blockIdx.x * 64, c0 = blockIdx.y * 64, b = blockIdx.z;
    const int nl = t & 63, cg = t >> 6;
#pragma unroll
    for (int i = 0; i < 16; ++i) {
        int cl = cg + i * 4;
        T[cl][nl] = src[((size_t)b * 256 + c0 + cl) * HW + n0 + nl];
    }
    __syncthreads();
#pragma unroll
    for (int i = 0; i < 16; ++i) {
        int nl2 = cg + i * 4;
        dst[((size_t)b * HW + n0 + nl2) * 256 + c0 + (t & 63)] = f2bf(T[t & 63][nl2]);
    }
}

// MFMA GEMM, 128x128 tile, 4 waves 2x2, 16x16x32, BK=32.
// T4 counted-vmcnt depth-2 pipeline (r9) + epilogue diet (r10) +
// T5 setprio around MFMA cluster (this round).
__global__ __launch_bounds__(256) void gemm_mfma(
    const unsigned short* __restrict__ Abf,
    const unsigned short* __restrict__ Wbf,
    const float* __restrict__ bias,
    int K, int M,
    float* __restrict__ outCM,
    unsigned short* __restrict__ outCMh,
    unsigned short* __restrict__ outPM,
    const float* __restrict__ resCM,
    const unsigned short* __restrict__ resPM,
    int epi)
{
    __shared__ __align__(16) char SMEM[49152];     // 3 bufs x (A 8KB + B 8KB)
    const int tid = threadIdx.x;
    const int w = tid >> 6, l = tid & 63;
    const int n0 = blockIdx.x * 128;
    const int m0 = blockIdx.y * 128;
    const int bz = blockIdx.z;
    const int wpi = w >> 1, wcj = w & 1;
    const int lr = l & 15, lg = l >> 4;

    const unsigned short* Ab = Abf + (size_t)bz * HW * K;

    f32x4 acc[4][4];
#pragma unroll
    for (int i = 0; i < 4; ++i)
#pragma unroll
        for (int j = 0; j < 4; ++j) acc[i][j] = (f32x4)0.f;

    const int sko = (((l & 3) ^ ((l >> 3) & 3)) * 8);   // swizzled k-chunk (elems)
    const int rsw = (lr >> 1) & 3;                      // read-side XOR
    const int row_l = (l >> 2);

    const int c0 = w * 2, c1 = c0 + 1;
    const unsigned short* pA0 = Ab  + (size_t)(n0 + c0 * 16 + row_l) * K + sko;
    const unsigned short* pA1 = Ab  + (size_t)(n0 + c1 * 16 + row_l) * K + sko;
    const unsigned short* pB0 = Wbf + (size_t)(m0 + c0 * 16 + row_l) * K + sko;
    const unsigned short* pB1 = Wbf + (size_t)(m0 + c1 * 16 + row_l) * K + sko;
    const int dA0 = c0 * 1024, dA1 = c1 * 1024;
    const int dB0 = 8192 + c0 * 1024, dB1 = 8192 + c1 * 1024;

#define STAGE(buf, kk)                                                         \
    {                                                                          \
        gload16(pA0 + (kk), SMEM + (buf) * 16384 + dA0);                       \
        gload16(pB0 + (kk), SMEM + (buf) * 16384 + dB0);                       \
        gload16(pA1 + (kk), SMEM + (buf) * 16384 + dA1);                       \
        gload16(pB1 + (kk), SMEM + (buf) * 16384 + dB1);                       \
    }

    const int NS = K >> 5;
    STAGE(0, 0);
    if (NS > 1) STAGE(1, 32);
    int cur = 0;
    for (int t = 0; t < NS; ++t) {
        if (t + 1 < NS) asm volatile("s_waitcnt vmcnt(4)\n\ts_barrier" ::: "memory");
        else            asm volatile("s_waitcnt vmcnt(0)\n\ts_barrier" ::: "memory");
        if (t + 2 < NS) {
            int nb = cur + 2; if (nb >= 3) nb -= 3;
            STAGE(nb, (t + 2) * 32);
        }
        const short* Ac = (const short*)(SMEM + cur * 16384);
        const short* Bc = (const short*)(SMEM + cur * 16384 + 8192);
        s16x8 av[4], bv[4];
#pragma unroll
        for (int f = 0; f < 4; ++f) {
            av[f] = *(const s16x8*)&Ac[(wpi * 64 + f * 16 + lr) * 32 + (lg ^ rsw) * 8];
            bv[f] = *(const s16x8*)&Bc[(wcj * 64 + f * 16 + lr) * 32 + (lg ^ rsw) * 8];
        }
        __builtin_amdgcn_s_setprio(1);
#pragma unroll
        for (int fi = 0; fi < 4; ++fi)
#pragma unroll
            for (int fj = 0; fj < 4; ++fj)
                acc[fi][fj] = mfma_bf16(av[fi], bv[fj], acc[fi][fj]);
        __builtin_amdgcn_s_setprio(0);
        if (++cur == 3) cur = 0;
    }
#undef STAGE

    unsigned short* RP = (unsigned short*)SMEM;    // 128x128 bf16 PM repack
    if (outPM) __syncthreads();                    // protect SMEM reuse

#pragma unroll
    for (int fi = 0; fi < 4; ++fi) {
#pragma unroll
        for (int fj = 0; fj < 4; ++fj) {
            const int m = m0 + wcj * 64 + fj * 16 + lr;
            const int nl = wpi * 64 + fi * 16 + lg * 4;   // tile-local n base
            const float bs = bias[m];
            const size_t oc = ((size_t)bz * M + m) * HW + n0 + nl;
            float4 v4;
            float* vp = &v4.x;
#pragma unroll
            for (int r = 0; r < 4; ++r) vp[r] = acc[fi][fj][r] + bs;
            if (epi == E_GELU) {
                // x*sigmoid(1.702x): |err| <= 0.021 vs exact-erf GELU
#pragma unroll
                for (int r = 0; r < 4; ++r)
                    vp[r] = vp[r] / (1.f + __expf(-1.702f * vp[r]));
            } else if (epi == E_RES) {
                const float4 rv = *(const float4*)&resCM[oc];
                v4.x += rv.x; v4.y += rv.y; v4.z += rv.z; v4.w += rv.w;
            } else if (epi == E_RESPM) {
#pragma unroll
                for (int r = 0; r < 4; ++r)
                    vp[r] += bf2f(resPM[((size_t)bz * HW + n0 + nl + r) * 256 + m]);
            }
            if (outCM)  *(float4*)&outCM[oc] = v4;
            if (outCMh) {
                uint2 p;
                p.x = cvt_pk_bf16(v4.x, v4.y);
                p.y = cvt_pk_bf16(v4.z, v4.w);
                *(uint2*)&outCMh[oc] = p;
            }
            if (outPM) {
                const int ml = wcj * 64 + fj * 16 + lr;
                const unsigned p01 = cvt_pk_bf16(vp[0], vp[1]);
                const unsigned p23 = cvt_pk_bf16(vp[2], vp[3]);
                RP[(nl + 0) * 128 + ml] = (unsigned short)p01;
                RP[(nl + 1) * 128 + ml] = (unsigned short)(p01 >> 16);
                RP[(nl + 2) * 128 + ml] = (unsigned short)p23;
                RP[(nl + 3) * 128 + ml] = (unsigned short)(p23 >> 16);
            }
        }
    }

    if (outPM) {
        __syncthreads();
#pragma unroll
        for (int i = 0; i < 8; ++i) {
            const int flat = i * 4096 + tid * 16;          // byte offset in tile
            const int nl = flat >> 8;
            const int mlb = flat & 255;
            *(us16x8*)&outPM[((size_t)bz * HW + n0 + nl) * M + m0 + (mlb >> 1)] =
                *(const us16x8*)((const char*)RP + flat);
        }
    }
}

// Row-direction scans (dirs 0/1), register-prefetched. Taps+lam bf16
// (lam raw: sigmoid applied here); u bf16; y f32.
__global__ __launch_bounds__(256) void scan_dir(
    const unsigned short* __restrict__ w3,
    const unsigned short* __restrict__ lam,
    const unsigned short* __restrict__ u,
    float* __restrict__ y,
    int dir, int overwrite)
{
    const int wave = threadIdx.x >> 6;
    const int lane = threadIdx.x & 63;
    const int plane = blockIdx.x * 4 + wave;
    const int b = plane >> 8;
    const int c = plane & 255;

    const size_t base_w = (size_t)b * (1024 * HW) + (size_t)c * HW;
    const size_t base_u = ((size_t)b * CDIM + c) * HW;
    const size_t tapstr = (size_t)CDIM * HW;

    int p = (dir == 1) ? 63 : 0;
    size_t off = (size_t)p * WD + lane;
    float w0 = bf2f(w3[base_w + off]);
    float w1 = bf2f(w3[base_w + tapstr + off]);
    float w2 = bf2f(w3[base_w + 2 * tapstr + off]);
    float lmr = bf2f(lam[base_w + off]);
    float uu = bf2f(u[base_u + off]);
    float yv = overwrite ? 0.f : y[base_u + off];

    float h = 0.f;
    for (int s = 0; s < 64; ++s) {
        float nw0 = 0.f, nw1 = 0.f, nw2 = 0.f, nlm = 0.f, nuu = 0.f, nyv = 0.f;
        size_t noff = 0;
        if (s + 1 < 64) {
            const int pn = (dir == 1) ? (62 - s) : (s + 1);
            noff = (size_t)pn * WD + lane;
            nw0 = bf2f(w3[base_w + noff]);
            nw1 = bf2f(w3[base_w + tapstr + noff]);
            nw2 = bf2f(w3[base_w + 2 * tapstr + noff]);
            nlm = bf2f(lam[base_w + noff]);
            nuu = bf2f(u[base_u + noff]);
            if (!overwrite) nyv = y[base_u + noff];
        }
        float dn = 1.0f / (fabsf(w0) + fabsf(w1) + fabsf(w2) + 1e-6f);
        float lm = 1.f / (1.f + __expf(-lmr));           // sigmoid moved here
        float hl = __shfl_up(h, 1);
        float hr = __shfl_down(h, 1);
        if (lane == 0)  hl = 0.f;
        if (lane == 63) hr = 0.f;
        h = (w0 * hl + w1 * h + w2 * hr) * dn + lm * uu;
        y[base_u + off] = yv + h;
        off = noff;
        w0 = nw0; w1 = nw1; w2 = nw2; lmr = nlm; uu = nuu; yv = nyv;
    }
}

// Column-direction scans (dirs 2/3), v3 (r11): CHT=32 full-line chunks,
// column-major LDS. u now bf16 (staged like taps); lam sigmoid here.
__global__ __launch_bounds__(128) void scan_dir_t(
    const unsigned short* __restrict__ w3,
    const unsigned short* __restrict__ lam,
    const unsigned short* __restrict__ u,
    float* __restrict__ y,
    int dir)
{
    __shared__ unsigned short TH[2][4][CHT][66];   // 33.0 KB
    __shared__ float U[2][CHT][65];                // 16.25 KB
    const int wv = threadIdx.x >> 6;
    const int lane = threadIdx.x & 63;
    const int plane = blockIdx.x * 2 + wv;
    const int b = plane >> 8;
    const int c = plane & 255;

    const size_t base_w = (size_t)b * (1024 * HW) + (size_t)c * HW;
    const size_t base_u = ((size_t)b * CDIM + c) * HW;
    const size_t tapstr = (size_t)CDIM * HW;
    const int rr4 = lane >> 2, q4 = lane & 3;      // bf16: 4 lanes/row, 16B each
    const int rr8 = lane >> 3, q8 = lane & 7;      // y f32: 8 lanes/row, 16B each

    float h = 0.f;
    for (int ci = 0; ci < 2; ++ci) {
        const int p0 = (dir == 3) ? (CHT - ci * CHT) : (ci * CHT);

        // stage taps+lam (bf16, full 64B-line reads, transpose-scatter)
#pragma unroll
        for (int a = 0; a < 4; ++a) {
            const unsigned short* s = (a < 3) ? (w3 + base_w + a * tapstr)
                                              : (lam + base_w);
#pragma unroll
            for (int i = 0; i < 4; ++i) {
                const int r = i * 16 + rr4;
                const us16x8 v = *(const us16x8*)(s + (size_t)r * WD + p0 + q4 * 8);
#pragma unroll
                for (int j = 0; j < 8; ++j) TH[wv][a][q4 * 8 + j][r] = v[j];
            }
        }
        // stage u (bf16 reads -> f32 LDS)
#pragma unroll
        for (int i = 0; i < 4; ++i) {
            const int r = i * 16 + rr4;
            const us16x8 v = *(const us16x8*)(u + base_u + (size_t)r * WD + p0 + q4 * 8);
#pragma unroll
            for (int j = 0; j < 8; ++j) U[wv][q4 * 8 + j][r] = bf2f(v[j]);
        }
        // same-wave LDS ops in-order; no cross-wave sharing -> no barrier

        for (int t = 0; t < CHT; ++t) {
            const int pp = (dir == 3) ? (CHT - 1 - t) : t;
            float w0 = bf2f(TH[wv][0][pp][lane]);
            float w1 = bf2f(TH[wv][1][pp][lane]);
            float w2 = bf2f(TH[wv][2][pp][lane]);
            float dn = 1.0f / (fabsf(w0) + fabsf(w1) + fabsf(w2) + 1e-6f);
            float lm = 1.f / (1.f + __expf(-bf2f(TH[wv][3][pp][lane])));
            float uu = U[wv][pp][lane];

            float hl = __shfl_up(h, 1);
            float hr = __shfl_down(h, 1);
            if (lane == 0)  hl = 0.f;
            if (lane == 63) hr = 0.f;

            h = (w0 * hl + w1 * h + w2 * hr) * dn + lm * uu;
            U[wv][pp][lane] = h;                   // overwrite consumed u slot
        }

        // coalesced float4 RMW of y
#pragma unroll
        for (int i = 0; i < 8; ++i) {
            const int r = i * 8 + rr8;
            const size_t g = base_u + (size_t)r * WD + p0 + q8 * 4;
            float4 old = *(const float4*)(y + g);
            old.x += U[wv][q8 * 4 + 0][r];
            old.y += U[wv][q8 * 4 + 1][r];
            old.z += U[wv][q8 * 4 + 2][r];
            old.w += U[wv][q8 * 4 + 3][r];
            *(float4*)(y + g) = old;
        }
    }
}

extern "C" void kernel_launch(void* const* d_in, const int* in_sizes, int n_in,
                              void* d_out, int out_size, void* d_ws, size_t ws_size,
                              hipStream_t stream)
{
    const float* x  = (const float*)d_in[0];
    const float* Wu = (const float*)d_in[1];
    const float* bu = (const float*)d_in[2];
    const float* Ww = (const float*)d_in[3];
    const float* bw = (const float*)d_in[4];
    const float* Wl = (const float*)d_in[5];
    const float* bl = (const float*)d_in[6];
    const float* Wo = (const float*)d_in[7];
    const float* bo = (const float*)d_in[8];
    const float* W1 = (const float*)d_in[9];
    const float* b1 = (const float*)d_in[10];
    const float* W2 = (const float*)d_in[11];
    const float* b2 = (const float*)d_in[12];
    float* out = (float*)d_out;

    // ws layout (~171 MB; >=188 proven):
    unsigned short* wlh = (unsigned short*)d_ws;            // [8][1024][4096] bf16 taps+lam(raw)
    unsigned short* uh  = wlh + 33554432;                   // [8][256][4096] bf16 u
    float* y_  = (float*)(uh + 8388608);                    // [8][256][4096] f32
    unsigned short* xT  = (unsigned short*)(y_ + 8388608);  // [8][4096][256] bf16
    unsigned short* yT  = xT + 8388608;
    unsigned short* x2T = yT + 8388608;
    unsigned short* Wt  = x2T + 8388608;
    float* biasP = (float*)(Wt + 1703936);
    unsigned short* hT = wlh;                               // [8][4096][1024] bf16, alias

    dim3 blk(256);

    pack_weights<<<dim3(6656), blk, 0, stream>>>(Wu, Ww, Wl, Wo, W1, W2,
                                                 bu, bw, bl, bo, b1, b2, Wt, biasP);
    transpose_to_bf<<<dim3(64, 4, 8), blk, 0, stream>>>(x, xT);

    // u = Wu @ x + bu  (bf16 channel-major for scans)
    gemm_mfma<<<dim3(32, 2, 8), blk, 0, stream>>>(xT, Wt, biasP, 256, 256,
        nullptr, uh, nullptr, nullptr, nullptr, E_NONE);

    for (int dir = 0; dir < 4; ++dir) {
        // fused taps(768)+lam(256) GEMM -> bf16 CM; lam stored raw (sigmoid in scan)
        gemm_mfma<<<dim3(32, 8, 8), blk, 0, stream>>>(
            xT, Wt + 65536 + (size_t)dir * 262144, biasP + 256 + dir * 1024,
            256, 1024, nullptr, wlh, nullptr, nullptr, nullptr, E_NONE);
        if (dir < 2)
            scan_dir<<<dim3(512), blk, 0, stream>>>(wlh, wlh + 3145728, uh, y_,
                                                    dir, dir == 0 ? 1 : 0);
        else
            scan_dir_t<<<dim3(1024), dim3(128), 0, stream>>>(wlh, wlh + 3145728,
                                                             uh, y_, dir);
    }

    transpose_to_bf<<<dim3(64, 4, 8), blk, 0, stream>>>(y_, yT);

    // x2 = x + Wo @ y + bo : bf16 PM only
    gemm_mfma<<<dim3(32, 2, 8), blk, 0, stream>>>(yT, Wt + 1114112, biasP + 4352,
        256, 256, nullptr, nullptr, x2T, x, nullptr, E_RES);
    // h = gelu(x2 @ W1 + b1) : bf16 PM only
    gemm_mfma<<<dim3(32, 8, 8), blk, 0, stream>>>(x2T, Wt + 1179648, biasP + 4608,
        256, 1024, nullptr, nullptr, hT, nullptr, nullptr, E_GELU);
    // out = x2 + h @ W2 + b2 : f32 CM = d_out, residual from x2T (PM bf16)
    gemm_mfma<<<dim3(32, 2, 8), blk, 0, stream>>>(hT, Wt + 1441792, biasP + 5632,
        1024, 256, out, nullptr, nullptr, nullptr, x2T, E_RESPM);
}

// Round 13
// 420.886 us; speedup vs baseline: 10.1491x; 1.0096x over previous
//
#include <hip/hip_runtime.h>
#include <hip/hip_bf16.h>
#include <math.h>

#define HW 4096
#define WD 64
#define CDIM 256
#define BATCH 8
#define CHT 32

typedef __attribute__((ext_vector_type(8))) short s16x8;
typedef __attribute__((ext_vector_type(8))) __bf16 b16x8;
typedef __attribute__((ext_vector_type(4))) float f32x4;
typedef __attribute__((ext_vector_type(8))) unsigned short us16x8;

enum { E_NONE = 0, E_GELU = 2, E_RES = 3, E_RESPM = 4 };

__device__ __forceinline__ unsigned short f2bf(float f) {
    union { float f; unsigned u; } v; v.f = f;
    unsigned r = (v.u + 0x7fffu + ((v.u >> 16) & 1u)) >> 16;
    return (unsigned short)r;
}
__device__ __forceinline__ float bf2f(unsigned short h) {
    union { unsigned u; float f; } v; v.u = ((unsigned)h) << 16; return v.f;
}
// D.lo16 = bf16(lo), D.hi16 = bf16(hi); RNE. No builtin on gfx950 -> asm.
__device__ __forceinline__ unsigned cvt_pk_bf16(float lo, float hi) {
    unsigned r;
    asm("v_cvt_pk_bf16_f32 %0, %1, %2" : "=v"(r) : "v"(lo), "v"(hi));
    return r;
}

__device__ __forceinline__ void gload16(const void* g, void* l) {
    __builtin_amdgcn_global_load_lds(
        (const __attribute__((address_space(1))) void*)g,
        (__attribute__((address_space(3))) void*)l, 16, 0, 0);
}

__device__ __forceinline__ f32x4 mfma_bf16(s16x8 a, s16x8 b, f32x4 c) {
    return __builtin_amdgcn_mfma_f32_16x16x32_bf16(
        __builtin_bit_cast(b16x8, a), __builtin_bit_cast(b16x8, b), c, 0, 0, 0);
}

// Pack all weights to bf16 [M][K] row-major blocks + packed bias vector.
__global__ __launch_bounds__(256) void pack_weights(
    const float* __restrict__ Wu, const float* __restrict__ Ww,
    const float* __restrict__ Wl, const float* __restrict__ Wo,
    const float* __restrict__ W1, const float* __restrict__ W2,
    const float* __restrict__ bu, const float* __restrict__ bw,
    const float* __restrict__ bl, const float* __restrict__ bo,
    const float* __restrict__ b1, const float* __restrict__ b2,
    unsigned short* __restrict__ Wt, float* __restrict__ biasP)
{
    const int gid = blockIdx.x * 256 + threadIdx.x;
    if (gid < 1703936) {
        float v;
        if (gid < 65536) { v = Wu[gid]; }
        else if (gid < 1114112) {
            int t = gid - 65536; int d = t >> 18; int r = t & 262143;
            int m = r >> 8; int k = r & 255;
            v = (m < 768) ? Ww[(size_t)(d * 768 + m) * 256 + k]
                          : Wl[(size_t)(d * 256 + (m - 768)) * 256 + k];
        }
        else if (gid < 1179648) { v = Wo[gid - 1114112]; }
        else if (gid < 1441792) {
            int t = gid - 1179648; int m = t >> 8; int k = t & 255;
            v = W1[(size_t)k * 1024 + m];
        }
        else {
            int t = gid - 1441792; int m = t >> 10; int k = t & 1023;
            v = W2[(size_t)k * 256 + m];
        }
        Wt[gid] = f2bf(v);
    }
    if (gid < 5888) {
        float v;
        if (gid < 256) v = bu[gid];
        else if (gid < 4352) {
            int t = gid - 256; int d = t >> 10; int r = t & 1023;
            v = (r < 768) ? bw[d * 768 + r] : bl[d * 256 + (r - 768)];
        }
        else if (gid < 4608) v = bo[gid - 4352];
        else if (gid < 5632) v = b1[gid - 4608];
        else v = b2[gid - 5632];
        biasP[gid] = v;
    }
}

// fp32 channel-major [B][256][4096] -> bf16 pixel-major [B][4096][256]
__global__ __launch_bounds__(256) void transpose_to_bf(
    const float* __restrict__ src, unsigned short* __restrict__ dst)
{
    __shared__ float T[64][65];
    const int t = threadIdx.x;
    const int n0 = blockIdx.x * 64, c0 = blockIdx.y * 64, b = blockIdx.z;
    const int nl = t & 63, cg = t >> 6;
#pragma unroll
    for (int i = 0; i < 16; ++i) {
        int cl = cg + i * 4;
        T[cl][nl] = src[((size_t)b * 256 + c0 + cl) * HW + n0 + nl];
    }
    __syncthreads();
#pragma unroll
    for (int i = 0; i < 16; ++i) {
        int nl2 = cg + i * 4;
        dst[((size_t)b * HW + n0 + nl2) * 256 + c0 + (t & 63)] = f2bf(T[t & 63][nl2]);
    }
}

// MFMA GEMM, 128x128 tile, 4 waves 2x2, 16x16x32, BK=32.
// r13: 2-buffer counted pipeline (32 KB LDS, was 49 KB/3-buf) to raise
// blocks/CU 3->5. Per iter: STAGE(t+1 -> cur^1); vmcnt(4) [drains own
// stage-t loads]; barrier [publishes all waves' stage-t]; MFMA(cur);
// barrier [protects cur from next iter's STAGE overwrite].
__global__ __launch_bounds__(256) void gemm_mfma(
    const unsigned short* __restrict__ Abf,
    const unsigned short* __restrict__ Wbf,
    const float* __restrict__ bias,
    int K, int M,
    float* __restrict__ outCM,
    unsigned short* __restrict__ outCMh,
    unsigned short* __restrict__ outPM,
    const float* __restrict__ resCM,
    const unsigned short* __restrict__ resPM,
    int epi)
{
    __shared__ __align__(16) char SMEM[32768];     // 2 bufs x (A 8KB + B 8KB)
    const int tid = threadIdx.x;
    const int w = tid >> 6, l = tid & 63;
    const int n0 = blockIdx.x * 128;
    const int m0 = blockIdx.y * 128;
    const int bz = blockIdx.z;
    const int wpi = w >> 1, wcj = w & 1;
    const int lr = l & 15, lg = l >> 4;

    const unsigned short* Ab = Abf + (size_t)bz * HW * K;

    f32x4 acc[4][4];
#pragma unroll
    for (int i = 0; i < 4; ++i)
#pragma unroll
        for (int j = 0; j < 4; ++j) acc[i][j] = (f32x4)0.f;

    const int sko = (((l & 3) ^ ((l >> 3) & 3)) * 8);   // swizzled k-chunk (elems)
    const int rsw = (lr >> 1) & 3;                      // read-side XOR
    const int row_l = (l >> 2);

    const int c0 = w * 2, c1 = c0 + 1;
    const unsigned short* pA0 = Ab  + (size_t)(n0 + c0 * 16 + row_l) * K + sko;
    const unsigned short* pA1 = Ab  + (size_t)(n0 + c1 * 16 + row_l) * K + sko;
    const unsigned short* pB0 = Wbf + (size_t)(m0 + c0 * 16 + row_l) * K + sko;
    const unsigned short* pB1 = Wbf + (size_t)(m0 + c1 * 16 + row_l) * K + sko;
    const int dA0 = c0 * 1024, dA1 = c1 * 1024;
    const int dB0 = 8192 + c0 * 1024, dB1 = 8192 + c1 * 1024;

#define STAGE(buf, kk)                                                         \
    {                                                                          \
        gload16(pA0 + (kk), SMEM + (buf) * 16384 + dA0);                       \
        gload16(pB0 + (kk), SMEM + (buf) * 16384 + dB0);                       \
        gload16(pA1 + (kk), SMEM + (buf) * 16384 + dA1);                       \
        gload16(pB1 + (kk), SMEM + (buf) * 16384 + dB1);                       \
    }

    const int NS = K >> 5;
    STAGE(0, 0);
    int cur = 0;
    for (int t = 0; t < NS; ++t) {
        if (t + 1 < NS) {
            STAGE(cur ^ 1, (t + 1) * 32);
            asm volatile("s_waitcnt vmcnt(4)" ::: "memory");
        } else {
            asm volatile("s_waitcnt vmcnt(0)" ::: "memory");
        }
        __builtin_amdgcn_s_barrier();              // all waves' stage-t in LDS
        const short* Ac = (const short*)(SMEM + cur * 16384);
        const short* Bc = (const short*)(SMEM + cur * 16384 + 8192);
        s16x8 av[4], bv[4];
#pragma unroll
        for (int f = 0; f < 4; ++f) {
            av[f] = *(const s16x8*)&Ac[(wpi * 64 + f * 16 + lr) * 32 + (lg ^ rsw) * 8];
            bv[f] = *(const s16x8*)&Bc[(wcj * 64 + f * 16 + lr) * 32 + (lg ^ rsw) * 8];
        }
        __builtin_amdgcn_s_setprio(1);
#pragma unroll
        for (int fi = 0; fi < 4; ++fi)
#pragma unroll
            for (int fj = 0; fj < 4; ++fj)
                acc[fi][fj] = mfma_bf16(av[fi], bv[fj], acc[fi][fj]);
        __builtin_amdgcn_s_setprio(0);
        __builtin_amdgcn_s_barrier();              // cur free for next STAGE
        cur ^= 1;
    }
#undef STAGE

    unsigned short* RP = (unsigned short*)SMEM;    // 128x128 bf16 PM repack
    // last loop barrier already separates reads from RP reuse

#pragma unroll
    for (int fi = 0; fi < 4; ++fi) {
#pragma unroll
        for (int fj = 0; fj < 4; ++fj) {
            const int m = m0 + wcj * 64 + fj * 16 + lr;
            const int nl = wpi * 64 + fi * 16 + lg * 4;   // tile-local n base
            const float bs = bias[m];
            const size_t oc = ((size_t)bz * M + m) * HW + n0 + nl;
            float4 v4;
            float* vp = &v4.x;
#pragma unroll
            for (int r = 0; r < 4; ++r) vp[r] = acc[fi][fj][r] + bs;
            if (epi == E_GELU) {
                // x*sigmoid(1.702x): |err| <= 0.021 vs exact-erf GELU
#pragma unroll
                for (int r = 0; r < 4; ++r)
                    vp[r] = vp[r] / (1.f + __expf(-1.702f * vp[r]));
            } else if (epi == E_RES) {
                const float4 rv = *(const float4*)&resCM[oc];
                v4.x += rv.x; v4.y += rv.y; v4.z += rv.z; v4.w += rv.w;
            } else if (epi == E_RESPM) {
#pragma unroll
                for (int r = 0; r < 4; ++r)
                    vp[r] += bf2f(resPM[((size_t)bz * HW + n0 + nl + r) * 256 + m]);
            }
            if (outCM)  *(float4*)&outCM[oc] = v4;
            if (outCMh) {
                uint2 p;
                p.x = cvt_pk_bf16(v4.x, v4.y);
                p.y = cvt_pk_bf16(v4.z, v4.w);
                *(uint2*)&outCMh[oc] = p;
            }
            if (outPM) {
                const int ml = wcj * 64 + fj * 16 + lr;
                const unsigned p01 = cvt_pk_bf16(vp[0], vp[1]);
                const unsigned p23 = cvt_pk_bf16(vp[2], vp[3]);
                RP[(nl + 0) * 128 + ml] = (unsigned short)p01;
                RP[(nl + 1) * 128 + ml] = (unsigned short)(p01 >> 16);
                RP[(nl + 2) * 128 + ml] = (unsigned short)p23;
                RP[(nl + 3) * 128 + ml] = (unsigned short)(p23 >> 16);
            }
        }
    }

    if (outPM) {
        __syncthreads();
#pragma unroll
        for (int i = 0; i < 8; ++i) {
            const int flat = i * 4096 + tid * 16;          // byte offset in tile
            const int nl = flat >> 8;
            const int mlb = flat & 255;
            *(us16x8*)&outPM[((size_t)bz * HW + n0 + nl) * M + m0 + (mlb >> 1)] =
                *(const us16x8*)((const char*)RP + flat);
        }
    }
}

// Row-direction scans (dirs 0/1), register-prefetched. Taps+lam bf16
// (lam raw: sigmoid applied here); u bf16; y f32.
__global__ __launch_bounds__(256) void scan_dir(
    const unsigned short* __restrict__ w3,
    const unsigned short* __restrict__ lam,
    const unsigned short* __restrict__ u,
    float* __restrict__ y,
    int dir, int overwrite)
{
    const int wave = threadIdx.x >> 6;
    const int lane = threadIdx.x & 63;
    const int plane = blockIdx.x * 4 + wave;
    const int b = plane >> 8;
    const int c = plane & 255;

    const size_t base_w = (size_t)b * (1024 * HW) + (size_t)c * HW;
    const size_t base_u = ((size_t)b * CDIM + c) * HW;
    const size_t tapstr = (size_t)CDIM * HW;

    int p = (dir == 1) ? 63 : 0;
    size_t off = (size_t)p * WD + lane;
    float w0 = bf2f(w3[base_w + off]);
    float w1 = bf2f(w3[base_w + tapstr + off]);
    float w2 = bf2f(w3[base_w + 2 * tapstr + off]);
    float lmr = bf2f(lam[base_w + off]);
    float uu = bf2f(u[base_u + off]);
    float yv = overwrite ? 0.f : y[base_u + off];

    float h = 0.f;
    for (int s = 0; s < 64; ++s) {
        float nw0 = 0.f, nw1 = 0.f, nw2 = 0.f, nlm = 0.f, nuu = 0.f, nyv = 0.f;
        size_t noff = 0;
        if (s + 1 < 64) {
            const int pn = (dir == 1) ? (62 - s) : (s + 1);
            noff = (size_t)pn * WD + lane;
            nw0 = bf2f(w3[base_w + noff]);
            nw1 = bf2f(w3[base_w + tapstr + noff]);
            nw2 = bf2f(w3[base_w + 2 * tapstr + noff]);
            nlm = bf2f(lam[base_w + noff]);
            nuu = bf2f(u[base_u + noff]);
            if (!overwrite) nyv = y[base_u + noff];
        }
        float dn = 1.0f / (fabsf(w0) + fabsf(w1) + fabsf(w2) + 1e-6f);
        float lm = 1.f / (1.f + __expf(-lmr));           // sigmoid here
        float hl = __shfl_up(h, 1);
        float hr = __shfl_down(h, 1);
        if (lane == 0)  hl = 0.f;
        if (lane == 63) hr = 0.f;
        h = (w0 * hl + w1 * h + w2 * hr) * dn + lm * uu;
        y[base_u + off] = yv + h;
        off = noff;
        w0 = nw0; w1 = nw1; w2 = nw2; lmr = nlm; uu = nuu; yv = nyv;
    }
}

// Column-direction scans (dirs 2/3), v4: CHT=32 full-line chunks,
// column-major LDS + T14 register-prefetch of chunk B (issued before
// chunk-A scan; HBM latency hides under 32 serial scan steps).
__global__ __launch_bounds__(128) void scan_dir_t(
    const unsigned short* __restrict__ w3,
    const unsigned short* __restrict__ lam,
    const unsigned short* __restrict__ u,
    float* __restrict__ y,
    int dir)
{
    __shared__ unsigned short TH[2][4][CHT][66];   // 33.0 KB
    __shared__ float U[2][CHT][65];                // 16.25 KB
    const int wv = threadIdx.x >> 6;
    const int lane = threadIdx.x & 63;
    const int plane = blockIdx.x * 2 + wv;
    const int b = plane >> 8;
    const int c = plane & 255;

    const size_t base_w = (size_t)b * (1024 * HW) + (size_t)c * HW;
    const size_t base_u = ((size_t)b * CDIM + c) * HW;
    const size_t tapstr = (size_t)CDIM * HW;
    const int rr4 = lane >> 2, q4 = lane & 3;      // bf16: 4 lanes/row, 16B each
    const int rr8 = lane >> 3, q8 = lane & 7;      // y f32: 8 lanes/row, 16B each

    const int p0A = (dir == 3) ? CHT : 0;
    const int p0B = CHT - p0A;

    // ---- stage chunk A directly into LDS
#pragma unroll
    for (int a = 0; a < 4; ++a) {
        const unsigned short* s = (a < 3) ? (w3 + base_w + a * tapstr)
                                          : (lam + base_w);
#pragma unroll
        for (int i = 0; i < 4; ++i) {
            const int r = i * 16 + rr4;
            const us16x8 v = *(const us16x8*)(s + (size_t)r * WD + p0A + q4 * 8);
#pragma unroll
            for (int j = 0; j < 8; ++j) TH[wv][a][q4 * 8 + j][r] = v[j];
        }
    }
#pragma unroll
    for (int i = 0; i < 4; ++i) {
        const int r = i * 16 + rr4;
        const us16x8 v = *(const us16x8*)(u + base_u + (size_t)r * WD + p0A + q4 * 8);
#pragma unroll
        for (int j = 0; j < 8; ++j) U[wv][q4 * 8 + j][r] = bf2f(v[j]);
    }

    // ---- prefetch chunk B into registers (use deferred until after scan A)
    us16x8 pfT[4][4], pfU[4];
#pragma unroll
    for (int a = 0; a < 4; ++a) {
        const unsigned short* s = (a < 3) ? (w3 + base_w + a * tapstr)
                                          : (lam + base_w);
#pragma unroll
        for (int i = 0; i < 4; ++i)
            pfT[a][i] = *(const us16x8*)(s + (size_t)(i * 16 + rr4) * WD + p0B + q4 * 8);
    }
#pragma unroll
    for (int i = 0; i < 4; ++i)
        pfU[i] = *(const us16x8*)(u + base_u + (size_t)(i * 16 + rr4) * WD + p0B + q4 * 8);

    float h = 0.f;

    auto SCAN = [&]() {
        for (int t = 0; t < CHT; ++t) {
            const int pp = (dir == 3) ? (CHT - 1 - t) : t;
            float w0 = bf2f(TH[wv][0][pp][lane]);
            float w1 = bf2f(TH[wv][1][pp][lane]);
            float w2 = bf2f(TH[wv][2][pp][lane]);
            float dn = 1.0f / (fabsf(w0) + fabsf(w1) + fabsf(w2) + 1e-6f);
            float lm = 1.f / (1.f + __expf(-bf2f(TH[wv][3][pp][lane])));
            float uu = U[wv][pp][lane];

            float hl = __shfl_up(h, 1);
            float hr = __shfl_down(h, 1);
            if (lane == 0)  hl = 0.f;
            if (lane == 63) hr = 0.f;

            h = (w0 * hl + w1 * h + w2 * hr) * dn + lm * uu;
            U[wv][pp][lane] = h;               // overwrite consumed u slot
        }
    };
    auto YRMW = [&](int p0) {
#pragma unroll
        for (int i = 0; i < 8; ++i) {
            const int r = i * 8 + rr8;
            const size_t g = base_u + (size_t)r * WD + p0 + q8 * 4;
            float4 old = *(const float4*)(y + g);
            old.x += U[wv][q8 * 4 + 0][r];
            old.y += U[wv][q8 * 4 + 1][r];
            old.z += U[wv][q8 * 4 + 2][r];
            old.w += U[wv][q8 * 4 + 3][r];
            *(float4*)(y + g) = old;
        }
    };

    SCAN();
    YRMW(p0A);

    // ---- commit prefetched chunk B to LDS (same-wave in-order; U free now)
#pragma unroll
    for (int a = 0; a < 4; ++a)
#pragma unroll
        for (int i = 0; i < 4; ++i) {
            const int r = i * 16 + rr4;
#pragma unroll
            for (int j = 0; j < 8; ++j) TH[wv][a][q4 * 8 + j][r] = pfT[a][i][j];
        }
#pragma unroll
    for (int i = 0; i < 4; ++i) {
        const int r = i * 16 + rr4;
#pragma unroll
        for (int j = 0; j < 8; ++j) U[wv][q4 * 8 + j][r] = bf2f(pfU[i][j]);
    }

    SCAN();
    YRMW(p0B);
}

extern "C" void kernel_launch(void* const* d_in, const int* in_sizes, int n_in,
                              void* d_out, int out_size, void* d_ws, size_t ws_size,
                              hipStream_t stream)
{
    const float* x  = (const float*)d_in[0];
    const float* Wu = (const float*)d_in[1];
    const float* bu = (const float*)d_in[2];
    const float* Ww = (const float*)d_in[3];
    const float* bw = (const float*)d_in[4];
    const float* Wl = (const float*)d_in[5];
    const float* bl = (const float*)d_in[6];
    const float* Wo = (const float*)d_in[7];
    const float* bo = (const float*)d_in[8];
    const float* W1 = (const float*)d_in[9];
    const float* b1 = (const float*)d_in[10];
    const float* W2 = (const float*)d_in[11];
    const float* b2 = (const float*)d_in[12];
    float* out = (float*)d_out;

    // ws layout (~171 MB; >=188 proven):
    unsigned short* wlh = (unsigned short*)d_ws;            // [8][1024][4096] bf16 taps+lam(raw)
    unsigned short* uh  = wlh + 33554432;                   // [8][256][4096] bf16 u
    float* y_  = (float*)(uh + 8388608);                    // [8][256][4096] f32
    unsigned short* xT  = (unsigned short*)(y_ + 8388608);  // [8][4096][256] bf16
    unsigned short* yT  = xT + 8388608;
    unsigned short* x2T = yT + 8388608;
    unsigned short* Wt  = x2T + 8388608;
    float* biasP = (float*)(Wt + 1703936);
    unsigned short* hT = wlh;                               // [8][4096][1024] bf16, alias

    dim3 blk(256);

    pack_weights<<<dim3(6656), blk, 0, stream>>>(Wu, Ww, Wl, Wo, W1, W2,
                                                 bu, bw, bl, bo, b1, b2, Wt, biasP);
    transpose_to_bf<<<dim3(64, 4, 8), blk, 0, stream>>>(x, xT);

    // u = Wu @ x + bu  (bf16 channel-major for scans)
    gemm_mfma<<<dim3(32, 2, 8), blk, 0, stream>>>(xT, Wt, biasP, 256, 256,
        nullptr, uh, nullptr, nullptr, nullptr, E_NONE);

    for (int dir = 0; dir < 4; ++dir) {
        // fused taps(768)+lam(256) GEMM -> bf16 CM; lam stored raw (sigmoid in scan)
        gemm_mfma<<<dim3(32, 8, 8), blk, 0, stream>>>(
            xT, Wt + 65536 + (size_t)dir * 262144, biasP + 256 + dir * 1024,
            256, 1024, nullptr, wlh, nullptr, nullptr, nullptr, E_NONE);
        if (dir < 2)
            scan_dir<<<dim3(512), blk, 0, stream>>>(wlh, wlh + 3145728, uh, y_,
                                                    dir, dir == 0 ? 1 : 0);
        else
            scan_dir_t<<<dim3(1024), dim3(128), 0, stream>>>(wlh, wlh + 3145728,
                                                             uh, y_, dir);
    }

    transpose_to_bf<<<dim3(64, 4, 8), blk, 0, stream>>>(y_, yT);

    // x2 = x + Wo @ y + bo : bf16 PM only
    gemm_mfma<<<dim3(32, 2, 8), blk, 0, stream>>>(yT, Wt + 1114112, biasP + 4352,
        256, 256, nullptr, nullptr, x2T, x, nullptr, E_RES);
    // h = gelu(x2 @ W1 + b1) : bf16 PM only
    gemm_mfma<<<dim3(32, 8, 8), blk, 0, stream>>>(x2T, Wt + 1179648, biasP + 4608,
        256, 1024, nullptr, nullptr, hT, nullptr, nullptr, E_GELU);
    // out = x2 + h @ W2 + b2 : f32 CM = d_out, residual from x2T (PM bf16)
    gemm_mfma<<<dim3(32, 2, 8), blk, 0, stream>>>(hT, Wt + 1441792, biasP + 5632,
        1024, 256, out, nullptr, nullptr, nullptr, x2T, E_RESPM);
}